// Round 5
// baseline (1204.820 us; speedup 1.0000x reference)
//
#include <hip/hip_runtime.h>
#include <math.h>

#define D 64
#define NBUCK 98          // buckets of 1024 nodes: bucket = dst >> 10
#define CAPB 17408        // fixed bucket capacity: mean 16384 + 8 sigma, 64B-aligned
#define BCAP 32           // LDS staging depth per bucket in partitionK
#define PART_BLOCKS 512
#define NWAVE 4

// ---- bf16 pack helpers (RNE) ----
__device__ __forceinline__ unsigned short f2bf(float f) {
  unsigned u = __float_as_uint(f);
  unsigned r = (u + 0x7fff + ((u >> 16) & 1)) >> 16;
  return (unsigned short)r;
}
__device__ __forceinline__ float bfLo(unsigned p) { return __uint_as_float(p << 16); }
__device__ __forceinline__ float bfHi(unsigned p) { return __uint_as_float(p & 0xffff0000u); }
__device__ __forceinline__ unsigned packYZ(float y, float z) {
  return (unsigned)f2bf(y) | ((unsigned)f2bf(z) << 16);
}

// ---------------- transforms (dense per-node GEMMs, wave = 64 output dims) ---

template <bool RELU>
__global__ __launch_bounds__(256) void transform64(
    const float* __restrict__ h, const float* __restrict__ Wm,
    const float* __restrict__ Bm, const float* __restrict__ Wr,
    const float* __restrict__ b, unsigned* __restrict__ yzp,
    float* __restrict__ agg, int n) {
  int wave = (blockIdx.x * 256 + threadIdx.x) >> 6;
  int lane = threadIdx.x & 63;
  int nb = wave << 2;
  if (nb >= n) return;
  float hv[4];
#pragma unroll
  for (int j = 0; j < 4; ++j) {
    int nn = nb + j;
    float v = (nn < n) ? h[(size_t)nn * D + lane] : 0.f;
    if (RELU) v = fmaxf(v, 0.f);
    hv[j] = v;
  }
  float ay[4] = {0.f, 0.f, 0.f, 0.f};
  float az[4] = {0.f, 0.f, 0.f, 0.f};
  float ar[4] = {0.f, 0.f, 0.f, 0.f};
#pragma unroll 8
  for (int k = 0; k < D; ++k) {
    float wm = Wm[k * D + lane];
    float wb = Bm[k * D + lane];
    float wr = Wr[k * D + lane];
#pragma unroll
    for (int j = 0; j < 4; ++j) {
      float hk = __shfl(hv[j], k, 64);
      ay[j] = fmaf(hk, wm, ay[j]);
      az[j] = fmaf(hk, wb, az[j]);
      ar[j] = fmaf(hk, wr, ar[j]);
    }
  }
  float bb = b[lane];
#pragma unroll
  for (int j = 0; j < 4; ++j) {
    int nn = nb + j;
    if (nn >= n) break;
    yzp[(size_t)nn * 64 + lane] = packYZ(ay[j], az[j]);
    agg[(size_t)nn * D + lane] = ar[j] + bb;
  }
}

// Layer 3 transform: lanes 0..3 hold the 4 classes for y,z,r.
__global__ __launch_bounds__(256) void transform3(
    const float* __restrict__ h, const float* __restrict__ Wm,
    const float* __restrict__ Bm, const float* __restrict__ Wr,
    const float* __restrict__ b, unsigned* __restrict__ yz3p,
    float* __restrict__ agg3, int n) {
  int wave = (blockIdx.x * 256 + threadIdx.x) >> 6;
  int lane = threadIdx.x & 63;
  int nb = wave << 2;
  if (nb >= n) return;
  int o = lane & 3;
  float hv[4];
#pragma unroll
  for (int j = 0; j < 4; ++j) {
    int nn = nb + j;
    float v = (nn < n) ? h[(size_t)nn * D + lane] : 0.f;
    hv[j] = fmaxf(v, 0.f);
  }
  float accY[4] = {0.f, 0.f, 0.f, 0.f};
  float accZ[4] = {0.f, 0.f, 0.f, 0.f};
  float accR[4] = {0.f, 0.f, 0.f, 0.f};
#pragma unroll 8
  for (int k = 0; k < D; ++k) {
    float wm = Wm[k * 4 + o];
    float wb = Bm[k * 4 + o];
    float wr = Wr[k * 4 + o];
#pragma unroll
    for (int j = 0; j < 4; ++j) {
      float hk = __shfl(hv[j], k, 64);
      accY[j] = fmaf(hk, wm, accY[j]);
      accZ[j] = fmaf(hk, wb, accZ[j]);
      accR[j] = fmaf(hk, wr, accR[j]);
    }
  }
  if (lane < 4) {
    float bb = b[o];
#pragma unroll
    for (int j = 0; j < 4; ++j) {
      int nn = nb + j;
      if (nn >= n) break;
      yz3p[(size_t)nn * 4 + o] = packYZ(accY[j], accZ[j]);
      agg3[(size_t)nn * 4 + o] = accR[j] + bb;
    }
  }
}

// ---------------- CSR build: initCur -> partition -> place -------------------

__global__ void initCur(int* __restrict__ gCur) {
  int t = threadIdx.x;
  if (t < NBUCK) gCur[t] = t * CAPB;
}

// LDS-staged partition, wave-cooperative flush. Entry = (src | dstLocal<<20, ea).
// Flushes in groups of 8 entries (64B lines) at 64B-aligned gCur offsets.
__global__ __launch_bounds__(256) void partitionK(
    const int* __restrict__ ei, const float* __restrict__ ea,
    int* __restrict__ gCur, uint2* __restrict__ edgesP, int ne) {
  __shared__ uint2 buf[NBUCK * BCAP];
  __shared__ int cnt[NBUCK];
  int t = threadIdx.x;
  int lane = t & 63, wid = t >> 6;
  if (t < NBUCK) cnt[t] = 0;
  __syncthreads();
  int chunk = (ne + PART_BLOCKS - 1) / PART_BLOCKS;
  int e0 = blockIdx.x * chunk;
  int e1 = min(ne, e0 + chunk);
  for (int base = e0; base < e1; base += 256) {
    int e = base + t;
    if (e < e1) {
      unsigned s = (unsigned)ei[e];
      int dd = ei[ne + e];
      unsigned abits = __float_as_uint(ea[e]);
      int bk = dd >> 10;
      uint2 ent = make_uint2(s | ((unsigned)(dd & 1023) << 20), abits);
      int pos = atomicAdd(&cnt[bk], 1);
      if (pos < BCAP) {
        buf[bk * BCAP + pos] = ent;
      } else {  // overflow fallback (statistically ~never)
        int g = atomicAdd(&gCur[bk], 1);
        edgesP[g] = ent;
      }
    }
    __syncthreads();
    // wave-cooperative flush: wave wid owns buckets wid, wid+4, ...
    for (int b = wid; b < NBUCK; b += NWAVE) {
      int c = min(cnt[b], BCAP);
      int g8 = c & ~7;
      if (g8) {
        int gb = 0;
        if (lane == 0) gb = atomicAdd(&gCur[b], g8);
        gb = __shfl(gb, 0, 64);
        if (lane < g8) edgesP[gb + lane] = buf[b * BCAP + lane];  // g8<=32
        int rem = c - g8;
        if (lane < rem) buf[b * BCAP + lane] = buf[b * BCAP + g8 + lane];
        if (lane == 0) cnt[b] = rem;
      }
    }
    __syncthreads();
  }
  // final tail flush (<8 entries per bucket)
  for (int b = wid; b < NBUCK; b += NWAVE) {
    int c = min(cnt[b], BCAP);
    if (c) {
      int gb = 0;
      if (lane == 0) gb = atomicAdd(&gCur[b], c);
      gb = __shfl(gb, 0, 64);
      if (lane < c) edgesP[gb + lane] = buf[b * BCAP + lane];
    }
  }
}

// One 1024-thread block per bucket: LDS deg hist -> 16-wave exclusive scan ->
// emit offS/offE (coalesced) -> place edges at exact CSR slots (writes stay
// inside this bucket's ~136KB region => full-line write-backs, single owner).
__global__ __launch_bounds__(1024) void placeK(
    const uint2* __restrict__ edgesP, const int* __restrict__ gCur,
    uint2* __restrict__ edgeS, int* __restrict__ offS, int* __restrict__ offE,
    int n) {
  __shared__ int deg[1024];
  __shared__ int cur[1024];
  __shared__ int wsum[16];
  int b = blockIdx.x;
  int t = threadIdx.x;
  int base = b * CAPB;
  int cnt = gCur[b] - base;
  int n0 = b << 10;
  int nn = min(1024, n - n0);
  deg[t] = 0;
  __syncthreads();
  for (int i = t; i < cnt; i += 1024)
    atomicAdd(&deg[edgesP[base + i].x >> 20], 1);
  __syncthreads();
  int v = deg[t];
  int lane = t & 63, wid = t >> 6;
  int inc = v;
#pragma unroll
  for (int d2 = 1; d2 < 64; d2 <<= 1) {
    int u = __shfl_up(inc, d2, 64);
    if (lane >= d2) inc += u;
  }
  if (lane == 63) wsum[wid] = inc;
  __syncthreads();
  if (t == 0) {
    int a = 0;
#pragma unroll
    for (int w = 0; w < 16; ++w) { int tmp = wsum[w]; wsum[w] = a; a += tmp; }
  }
  __syncthreads();
  int excl = wsum[wid] + inc - v;
  cur[t] = excl;
  if (t < nn) {
    offS[n0 + t] = base + excl;
    offE[n0 + t] = base + excl + v;
  }
  __syncthreads();
  for (int i = t; i < cnt; i += 1024) {
    uint2 ent = edgesP[base + i];
    int dl = ent.x >> 20;
    int slot = base + atomicAdd(&cur[dl], 1);
    edgeS[slot] = make_uint2(ent.x & 0xFFFFFu, ent.y);
  }
}

// ---------------- gather-aggregate (conflict-free, one write per node) ------

__global__ __launch_bounds__(256) void gather64(
    const int* __restrict__ offS, const int* __restrict__ offE,
    const uint2* __restrict__ edgeS, const unsigned* __restrict__ yzp,
    float* __restrict__ agg, int n) {
  int node = (blockIdx.x * 256 + threadIdx.x) >> 6;
  int lane = threadIdx.x & 63;
  if (node >= n) return;
  // loop bounds are wave-uniform: force into SGPRs so edgeS reads can be scalar
  int j = __builtin_amdgcn_readfirstlane(offS[node]);
  int jend = __builtin_amdgcn_readfirstlane(offE[node]);
  float acc = agg[(size_t)node * 64 + lane];
#pragma unroll 1
  for (; j + 3 < jend; j += 4) {
    uint2 e0 = edgeS[j], e1 = edgeS[j + 1], e2 = edgeS[j + 2], e3 = edgeS[j + 3];
    unsigned p0 = yzp[(size_t)e0.x * 64 + lane];
    unsigned p1 = yzp[(size_t)e1.x * 64 + lane];
    unsigned p2 = yzp[(size_t)e2.x * 64 + lane];
    unsigned p3 = yzp[(size_t)e3.x * 64 + lane];
    acc += fmaf(__uint_as_float(e0.y), bfLo(p0), bfHi(p0));
    acc += fmaf(__uint_as_float(e1.y), bfLo(p1), bfHi(p1));
    acc += fmaf(__uint_as_float(e2.y), bfLo(p2), bfHi(p2));
    acc += fmaf(__uint_as_float(e3.y), bfLo(p3), bfHi(p3));
  }
#pragma unroll 1
  for (; j < jend; ++j) {
    uint2 e0 = edgeS[j];
    unsigned p0 = yzp[(size_t)e0.x * 64 + lane];
    acc += fmaf(__uint_as_float(e0.y), bfLo(p0), bfHi(p0));
  }
  agg[(size_t)node * 64 + lane] = acc;
}

// Layer 3: 4 lanes per node (o = class), fused log_softmax across the group.
__global__ __launch_bounds__(256) void gather4_logsm(
    const int* __restrict__ offS, const int* __restrict__ offE,
    const uint2* __restrict__ edgeS, const unsigned* __restrict__ yz3p,
    const float* __restrict__ agg3, float* __restrict__ out, int n) {
  int idx = blockIdx.x * 256 + threadIdx.x;
  int node = idx >> 2;
  int o = idx & 3;
  if (node >= n) return;
  int j = offS[node];
  int jend = offE[node];
  float acc = agg3[(size_t)node * 4 + o];
#pragma unroll 1
  for (; j < jend; ++j) {
    uint2 ed = edgeS[j];
    unsigned p = yz3p[(size_t)ed.x * 4 + o];
    acc += fmaf(__uint_as_float(ed.y), bfLo(p), bfHi(p));
  }
  float m = acc;
  m = fmaxf(m, __shfl_xor(m, 1, 4));
  m = fmaxf(m, __shfl_xor(m, 2, 4));
  float s = expf(acc - m);
  s += __shfl_xor(s, 1, 4);
  s += __shfl_xor(s, 2, 4);
  out[(size_t)node * 4 + o] = acc - m - logf(s);
}

// ---------------- launch -----------------------------------------------------

extern "C" void kernel_launch(void* const* d_in, const int* in_sizes, int n_in,
                              void* d_out, int out_size, void* d_ws, size_t ws_size,
                              hipStream_t stream) {
  const float* x = (const float*)d_in[0];
  const int* ei = (const int*)d_in[1];
  const float* ea = (const float*)d_in[2];
  const float* We1 = (const float*)d_in[3];
  const float* be1 = (const float*)d_in[4];
  const float* Wr1 = (const float*)d_in[5];
  const float* b1 = (const float*)d_in[6];
  const float* We2 = (const float*)d_in[7];
  const float* be2 = (const float*)d_in[8];
  const float* Wr2 = (const float*)d_in[9];
  const float* b2 = (const float*)d_in[10];
  const float* We3 = (const float*)d_in[11];
  const float* be3 = (const float*)d_in[12];
  const float* Wr3 = (const float*)d_in[13];
  const float* b3 = (const float*)d_in[14];

  const int N = in_sizes[0] / D;  // 100000
  const int E = in_sizes[2];      // 1600000
  const size_t EREG = (size_t)NBUCK * CAPB;  // padded CSR storage

  // ws layout. edgesP aliases agg2 (dead before layer-2 transform writes it);
  // agg3/yz3p alias agg1 (dead after layer-2 transform reads it).
  char* ws = (char*)d_ws;
  uint2* edgeS = (uint2*)ws;                                 // EREG * 8B
  unsigned* yzp = (unsigned*)(ws + EREG * 8);                // N*64 * 4B
  float* agg1 = (float*)((char*)yzp + (size_t)N * 64 * 4);   // N*64
  float* agg2 = agg1 + (size_t)N * 64;                       // N*64
  int* offS = (int*)(agg2 + (size_t)N * 64);                 // N
  int* offE = offS + N;                                      // N
  int* gCur = offE + N;                                      // 128
  uint2* edgesP = (uint2*)agg2;                              // alias (EREG<=N*64)
  float* agg3 = agg1;                                        // alias
  unsigned* yz3p = (unsigned*)(agg1 + (size_t)N * 4);        // alias
  float* out = (float*)d_out;

  int waves = (N + 3) / 4;
  int tblocks = (waves + 3) / 4;  // transform: 4 waves/block
  int g64blocks = (int)(((long long)N * 64 + 255) / 256);
  int g4blocks = (int)(((long long)N * 4 + 255) / 256);

  // ---- CSR build ----
  initCur<<<1, 128, 0, stream>>>(gCur);
  partitionK<<<PART_BLOCKS, 256, 0, stream>>>(ei, ea, gCur, edgesP, E);
  placeK<<<NBUCK, 1024, 0, stream>>>(edgesP, gCur, edgeS, offS, offE, N);

  // ---- Layer 1: x -> agg1 ----
  transform64<false><<<tblocks, 256, 0, stream>>>(x, We1, be1, Wr1, b1, yzp, agg1, N);
  gather64<<<g64blocks, 256, 0, stream>>>(offS, offE, edgeS, yzp, agg1, N);
  // ---- Layer 2: relu(agg1) -> agg2 ----
  transform64<true><<<tblocks, 256, 0, stream>>>(agg1, We2, be2, Wr2, b2, yzp, agg2, N);
  gather64<<<g64blocks, 256, 0, stream>>>(offS, offE, edgeS, yzp, agg2, N);
  // ---- Layer 3: relu(agg2) -> out (fused log_softmax) ----
  transform3<<<tblocks, 256, 0, stream>>>(agg2, We3, be3, Wr3, b3, yz3p, agg3, N);
  gather4_logsm<<<g4blocks, 256, 0, stream>>>(offS, offE, edgeS, yz3p, agg3, out, N);
}

// Round 6
// 520.007 us; speedup vs baseline: 2.3169x; 2.3169x over previous
//
#include <hip/hip_runtime.h>
#include <math.h>

#define D 64
#define NBUCK 392         // buckets of 256 nodes: bucket = dst >> 8 (392*256=100352)
#define CAPB 4736         // fixed bucket capacity: mean 4096 + 10 sigma, 8-entry aligned
#define PART_BLOCKS 256

// ---- bf16 pack helpers (RNE) ----
__device__ __forceinline__ unsigned short f2bf(float f) {
  unsigned u = __float_as_uint(f);
  unsigned r = (u + 0x7fff + ((u >> 16) & 1)) >> 16;
  return (unsigned short)r;
}
__device__ __forceinline__ float bfLo(unsigned p) { return __uint_as_float(p << 16); }
__device__ __forceinline__ float bfHi(unsigned p) { return __uint_as_float(p & 0xffff0000u); }
__device__ __forceinline__ unsigned packYZ(float y, float z) {
  return (unsigned)f2bf(y) | ((unsigned)f2bf(z) << 16);
}

// ---------------- transforms (dense per-node GEMMs, wave = 64 output dims) ---

template <bool RELU>
__global__ __launch_bounds__(256) void transform64(
    const float* __restrict__ h, const float* __restrict__ Wm,
    const float* __restrict__ Bm, const float* __restrict__ Wr,
    const float* __restrict__ b, unsigned* __restrict__ yzp,
    float* __restrict__ agg, int n) {
  int wave = (blockIdx.x * 256 + threadIdx.x) >> 6;
  int lane = threadIdx.x & 63;
  int nb = wave << 2;
  if (nb >= n) return;
  float hv[4];
#pragma unroll
  for (int j = 0; j < 4; ++j) {
    int nn = nb + j;
    float v = (nn < n) ? h[(size_t)nn * D + lane] : 0.f;
    if (RELU) v = fmaxf(v, 0.f);
    hv[j] = v;
  }
  float ay[4] = {0.f, 0.f, 0.f, 0.f};
  float az[4] = {0.f, 0.f, 0.f, 0.f};
  float ar[4] = {0.f, 0.f, 0.f, 0.f};
#pragma unroll 8
  for (int k = 0; k < D; ++k) {
    float wm = Wm[k * D + lane];
    float wb = Bm[k * D + lane];
    float wr = Wr[k * D + lane];
#pragma unroll
    for (int j = 0; j < 4; ++j) {
      float hk = __shfl(hv[j], k, 64);
      ay[j] = fmaf(hk, wm, ay[j]);
      az[j] = fmaf(hk, wb, az[j]);
      ar[j] = fmaf(hk, wr, ar[j]);
    }
  }
  float bb = b[lane];
#pragma unroll
  for (int j = 0; j < 4; ++j) {
    int nn = nb + j;
    if (nn >= n) break;
    yzp[(size_t)nn * 64 + lane] = packYZ(ay[j], az[j]);
    agg[(size_t)nn * D + lane] = ar[j] + bb;
  }
}

// Layer 3 transform: lanes 0..3 hold the 4 classes for y,z,r.
__global__ __launch_bounds__(256) void transform3(
    const float* __restrict__ h, const float* __restrict__ Wm,
    const float* __restrict__ Bm, const float* __restrict__ Wr,
    const float* __restrict__ b, unsigned* __restrict__ yz3p,
    float* __restrict__ agg3, int n) {
  int wave = (blockIdx.x * 256 + threadIdx.x) >> 6;
  int lane = threadIdx.x & 63;
  int nb = wave << 2;
  if (nb >= n) return;
  int o = lane & 3;
  float hv[4];
#pragma unroll
  for (int j = 0; j < 4; ++j) {
    int nn = nb + j;
    float v = (nn < n) ? h[(size_t)nn * D + lane] : 0.f;
    hv[j] = fmaxf(v, 0.f);
  }
  float accY[4] = {0.f, 0.f, 0.f, 0.f};
  float accZ[4] = {0.f, 0.f, 0.f, 0.f};
  float accR[4] = {0.f, 0.f, 0.f, 0.f};
#pragma unroll 8
  for (int k = 0; k < D; ++k) {
    float wm = Wm[k * 4 + o];
    float wb = Bm[k * 4 + o];
    float wr = Wr[k * 4 + o];
#pragma unroll
    for (int j = 0; j < 4; ++j) {
      float hk = __shfl(hv[j], k, 64);
      accY[j] = fmaf(hk, wm, accY[j]);
      accZ[j] = fmaf(hk, wb, accZ[j]);
      accR[j] = fmaf(hk, wr, accR[j]);
    }
  }
  if (lane < 4) {
    float bb = b[o];
#pragma unroll
    for (int j = 0; j < 4; ++j) {
      int nn = nb + j;
      if (nn >= n) break;
      yz3p[(size_t)nn * 4 + o] = packYZ(accY[j], accZ[j]);
      agg3[(size_t)nn * 4 + o] = accR[j] + bb;
    }
  }
}

// --------- CSR build: histA -> scanCols -> scatterC -> placeK ---------------
// Deterministic counting sort; NO global atomics anywhere.

// Per-block LDS histogram of this block's contiguous edge chunk.
__global__ __launch_bounds__(256) void histA(const int* __restrict__ ei,
                                             int* __restrict__ hist, int ne) {
  __shared__ int h[NBUCK];
  int t = threadIdx.x;
  for (int i = t; i < NBUCK; i += 256) h[i] = 0;
  __syncthreads();
  int chunk = (ne + PART_BLOCKS - 1) / PART_BLOCKS;
  int e0 = blockIdx.x * chunk;
  int e1 = min(ne, e0 + chunk);
  for (int e = e0 + t; e < e1; e += 256)
    atomicAdd(&h[ei[ne + e] >> 8], 1);
  __syncthreads();
  for (int i = t; i < NBUCK; i += 256) hist[blockIdx.x * NBUCK + i] = h[i];
}

// One block per bucket: exclusive-scan the 256 per-block counts of this
// bucket's column, in-place (hist[blk][b] becomes the absolute write base);
// emit bucket total.
__global__ __launch_bounds__(256) void scanCols(int* __restrict__ hist,
                                                int* __restrict__ gTotal) {
  __shared__ int wsum[4];
  int b = blockIdx.x;
  int t = threadIdx.x;
  int v = hist[t * NBUCK + b];
  int lane = t & 63, wid = t >> 6;
  int inc = v;
#pragma unroll
  for (int d = 1; d < 64; d <<= 1) {
    int u = __shfl_up(inc, d, 64);
    if (lane >= d) inc += u;
  }
  if (lane == 63) wsum[wid] = inc;
  __syncthreads();
  if (t == 0) {
    int a = 0;
#pragma unroll
    for (int w = 0; w < 4; ++w) { int tmp = wsum[w]; wsum[w] = a; a += tmp; }
  }
  __syncthreads();
  int excl = wsum[wid] + inc - v;
  hist[t * NBUCK + b] = b * CAPB + excl;
  if (t == 255) gTotal[b] = excl + v;
}

// Re-read chunk; slot = precomputed base + LDS-atomic position. Entry =
// (src | dstLocal<<20, ea_bits). Writes are ~sequential within each
// (block,bucket) window -> L2-hot full lines, single logical owner.
__global__ __launch_bounds__(256) void scatterC(
    const int* __restrict__ ei, const float* __restrict__ ea,
    const int* __restrict__ baseArr, uint2* __restrict__ edgesP, int ne) {
  __shared__ int cnt[NBUCK];
  __shared__ int lbase[NBUCK];
  int t = threadIdx.x;
  for (int i = t; i < NBUCK; i += 256) {
    cnt[i] = 0;
    lbase[i] = baseArr[blockIdx.x * NBUCK + i];
  }
  __syncthreads();
  int chunk = (ne + PART_BLOCKS - 1) / PART_BLOCKS;
  int e0 = blockIdx.x * chunk;
  int e1 = min(ne, e0 + chunk);
  for (int e = e0 + t; e < e1; e += 256) {
    unsigned s = (unsigned)ei[e];
    int dd = ei[ne + e];
    unsigned abits = __float_as_uint(ea[e]);
    int bk = dd >> 8;
    int pos = atomicAdd(&cnt[bk], 1);
    edgesP[lbase[bk] + pos] = make_uint2(s | ((unsigned)(dd & 255) << 20), abits);
  }
}

// One block per bucket: LDS deg hist -> exclusive scan -> emit offS/offE
// (coalesced) -> place edges at exact CSR slots (writes stay inside this
// bucket's ~37KB region => full-line write-backs, single owner).
__global__ __launch_bounds__(256) void placeK(
    const uint2* __restrict__ edgesP, const int* __restrict__ gTotal,
    uint2* __restrict__ edgeS, int* __restrict__ offS, int* __restrict__ offE,
    int n) {
  __shared__ int deg[256];
  __shared__ int cur[256];
  __shared__ int wsum[4];
  int b = blockIdx.x;
  int t = threadIdx.x;
  int base = b * CAPB;
  int cnt = gTotal[b];
  int n0 = b << 8;
  int nn = min(256, n - n0);
  deg[t] = 0;
  __syncthreads();
  for (int i = t; i < cnt; i += 256)
    atomicAdd(&deg[edgesP[base + i].x >> 20], 1);
  __syncthreads();
  int v = deg[t];
  int lane = t & 63, wid = t >> 6;
  int inc = v;
#pragma unroll
  for (int d2 = 1; d2 < 64; d2 <<= 1) {
    int u = __shfl_up(inc, d2, 64);
    if (lane >= d2) inc += u;
  }
  if (lane == 63) wsum[wid] = inc;
  __syncthreads();
  if (t == 0) {
    int a = 0;
#pragma unroll
    for (int w = 0; w < 4; ++w) { int tmp = wsum[w]; wsum[w] = a; a += tmp; }
  }
  __syncthreads();
  int excl = wsum[wid] + inc - v;
  cur[t] = excl;
  if (t < nn) {
    offS[n0 + t] = base + excl;
    offE[n0 + t] = base + excl + v;
  }
  __syncthreads();
  for (int i = t; i < cnt; i += 256) {
    uint2 ent = edgesP[base + i];
    int dl = ent.x >> 20;
    int slot = base + atomicAdd(&cur[dl], 1);
    edgeS[slot] = make_uint2(ent.x & 0xFFFFFu, ent.y);
  }
}

// ---------------- gather-aggregate (conflict-free, one write per node) ------

__global__ __launch_bounds__(256) void gather64(
    const int* __restrict__ offS, const int* __restrict__ offE,
    const uint2* __restrict__ edgeS, const unsigned* __restrict__ yzp,
    float* __restrict__ agg, int n) {
  int node = (blockIdx.x * 256 + threadIdx.x) >> 6;
  int lane = threadIdx.x & 63;
  if (node >= n) return;
  int j = offS[node];
  int jend = offE[node];
  float acc = agg[(size_t)node * 64 + lane];
#pragma unroll 1
  for (; j + 3 < jend; j += 4) {
    uint2 e0 = edgeS[j], e1 = edgeS[j + 1], e2 = edgeS[j + 2], e3 = edgeS[j + 3];
    unsigned p0 = yzp[(size_t)e0.x * 64 + lane];
    unsigned p1 = yzp[(size_t)e1.x * 64 + lane];
    unsigned p2 = yzp[(size_t)e2.x * 64 + lane];
    unsigned p3 = yzp[(size_t)e3.x * 64 + lane];
    acc += fmaf(__uint_as_float(e0.y), bfLo(p0), bfHi(p0));
    acc += fmaf(__uint_as_float(e1.y), bfLo(p1), bfHi(p1));
    acc += fmaf(__uint_as_float(e2.y), bfLo(p2), bfHi(p2));
    acc += fmaf(__uint_as_float(e3.y), bfLo(p3), bfHi(p3));
  }
#pragma unroll 1
  for (; j < jend; ++j) {
    uint2 e0 = edgeS[j];
    unsigned p0 = yzp[(size_t)e0.x * 64 + lane];
    acc += fmaf(__uint_as_float(e0.y), bfLo(p0), bfHi(p0));
  }
  agg[(size_t)node * 64 + lane] = acc;
}

// Layer 3: 4 lanes per node (o = class), fused log_softmax across the group.
__global__ __launch_bounds__(256) void gather4_logsm(
    const int* __restrict__ offS, const int* __restrict__ offE,
    const uint2* __restrict__ edgeS, const unsigned* __restrict__ yz3p,
    const float* __restrict__ agg3, float* __restrict__ out, int n) {
  int idx = blockIdx.x * 256 + threadIdx.x;
  int node = idx >> 2;
  int o = idx & 3;
  if (node >= n) return;
  int j = offS[node];
  int jend = offE[node];
  float acc = agg3[(size_t)node * 4 + o];
#pragma unroll 1
  for (; j < jend; ++j) {
    uint2 ed = edgeS[j];
    unsigned p = yz3p[(size_t)ed.x * 4 + o];
    acc += fmaf(__uint_as_float(ed.y), bfLo(p), bfHi(p));
  }
  float m = acc;
  m = fmaxf(m, __shfl_xor(m, 1, 4));
  m = fmaxf(m, __shfl_xor(m, 2, 4));
  float s = expf(acc - m);
  s += __shfl_xor(s, 1, 4);
  s += __shfl_xor(s, 2, 4);
  out[(size_t)node * 4 + o] = acc - m - logf(s);
}

// ---------------- launch -----------------------------------------------------

extern "C" void kernel_launch(void* const* d_in, const int* in_sizes, int n_in,
                              void* d_out, int out_size, void* d_ws, size_t ws_size,
                              hipStream_t stream) {
  const float* x = (const float*)d_in[0];
  const int* ei = (const int*)d_in[1];
  const float* ea = (const float*)d_in[2];
  const float* We1 = (const float*)d_in[3];
  const float* be1 = (const float*)d_in[4];
  const float* Wr1 = (const float*)d_in[5];
  const float* b1 = (const float*)d_in[6];
  const float* We2 = (const float*)d_in[7];
  const float* be2 = (const float*)d_in[8];
  const float* Wr2 = (const float*)d_in[9];
  const float* b2 = (const float*)d_in[10];
  const float* We3 = (const float*)d_in[11];
  const float* be3 = (const float*)d_in[12];
  const float* Wr3 = (const float*)d_in[13];
  const float* b3 = (const float*)d_in[14];

  const int N = in_sizes[0] / D;  // 100000
  const int E = in_sizes[2];      // 1600000
  const size_t EREG = (size_t)NBUCK * CAPB;  // padded CSR storage (~1.86M entries)

  // ws layout. edgesP aliases agg2 (dead before layer-2 transform writes it);
  // agg3/yz3p alias agg1 (dead after layer-2 transform reads it).
  char* ws = (char*)d_ws;
  uint2* edgeS = (uint2*)ws;                                 // EREG * 8B
  unsigned* yzp = (unsigned*)(ws + EREG * 8);                // N*64 * 4B
  float* agg1 = (float*)((char*)yzp + (size_t)N * 64 * 4);   // N*64
  float* agg2 = agg1 + (size_t)N * 64;                       // N*64
  int* offS = (int*)(agg2 + (size_t)N * 64);                 // N
  int* offE = offS + N;                                      // N
  int* gTotal = offE + N;                                    // NBUCK
  int* hist = gTotal + NBUCK;                                // PART_BLOCKS*NBUCK
  uint2* edgesP = (uint2*)agg2;                              // alias (EREG*8 <= N*64*4)
  float* agg3 = agg1;                                        // alias
  unsigned* yz3p = (unsigned*)(agg1 + (size_t)N * 4);        // alias
  float* out = (float*)d_out;

  int waves = (N + 3) / 4;
  int tblocks = (waves + 3) / 4;  // transform: 4 waves/block
  int g64blocks = (int)(((long long)N * 64 + 255) / 256);
  int g4blocks = (int)(((long long)N * 4 + 255) / 256);

  // ---- CSR build (deterministic counting sort, no global atomics) ----
  histA<<<PART_BLOCKS, 256, 0, stream>>>(ei, hist, E);
  scanCols<<<NBUCK, 256, 0, stream>>>(hist, gTotal);
  scatterC<<<PART_BLOCKS, 256, 0, stream>>>(ei, ea, hist, edgesP, E);
  placeK<<<NBUCK, 256, 0, stream>>>(edgesP, gTotal, edgeS, offS, offE, N);

  // ---- Layer 1: x -> agg1 ----
  transform64<false><<<tblocks, 256, 0, stream>>>(x, We1, be1, Wr1, b1, yzp, agg1, N);
  gather64<<<g64blocks, 256, 0, stream>>>(offS, offE, edgeS, yzp, agg1, N);
  // ---- Layer 2: relu(agg1) -> agg2 ----
  transform64<true><<<tblocks, 256, 0, stream>>>(agg1, We2, be2, Wr2, b2, yzp, agg2, N);
  gather64<<<g64blocks, 256, 0, stream>>>(offS, offE, edgeS, yzp, agg2, N);
  // ---- Layer 3: relu(agg2) -> out (fused log_softmax) ----
  transform3<<<tblocks, 256, 0, stream>>>(agg2, We3, be3, Wr3, b3, yz3p, agg3, N);
  gather4_logsm<<<g4blocks, 256, 0, stream>>>(offS, offE, edgeS, yz3p, agg3, out, N);
}

// Round 7
// 417.451 us; speedup vs baseline: 2.8861x; 1.2457x over previous
//
#include <hip/hip_runtime.h>
#include <math.h>

#define D 64
#define NBUCK 392         // buckets of 256 nodes: bucket = dst >> 8 (392*256=100352)
#define CAPB 4736         // fixed bucket capacity: mean 4096 + 10 sigma, 8-entry aligned
#define PART_BLOCKS 256

typedef __attribute__((ext_vector_type(4))) float f32x4;
typedef __attribute__((ext_vector_type(8))) short s16x8;

// ---- bf16 pack helpers (RNE) ----
__device__ __forceinline__ unsigned short f2bf(float f) {
  unsigned u = __float_as_uint(f);
  unsigned r = (u + 0x7fff + ((u >> 16) & 1)) >> 16;
  return (unsigned short)r;
}
__device__ __forceinline__ float bfLo(unsigned p) { return __uint_as_float(p << 16); }
__device__ __forceinline__ float bfHi(unsigned p) { return __uint_as_float(p & 0xffff0000u); }
__device__ __forceinline__ unsigned packYZ(float y, float z) {
  return (unsigned)f2bf(y) | ((unsigned)f2bf(z) << 16);
}

// ---------------- weight prep: Wt[l] = bf16 [192][64], rows = [Wm|Bm|Wr]^T ---

__global__ void wprep(const float* __restrict__ We1, const float* __restrict__ be1,
                      const float* __restrict__ Wr1, const float* __restrict__ We2,
                      const float* __restrict__ be2, const float* __restrict__ Wr2,
                      unsigned short* __restrict__ Wt) {
  int l = blockIdx.x;
  const float* We = l ? We2 : We1;
  const float* be = l ? be2 : be1;
  const float* Wr = l ? Wr2 : Wr1;
  unsigned short* w = Wt + l * 12288;
  for (int idx = threadIdx.x; idx < 12288; idx += 256) {
    int r = idx >> 6, k = idx & 63;
    int sel = r >> 6, o = r & 63;
    float v = (sel == 0) ? We[k * 64 + o] : (sel == 1) ? be[k * 64 + o] : Wr[k * 64 + o];
    Wt[l * 12288 + idx] = f2bf(v);
    (void)w;
  }
}

// ---------------- MFMA transform: [n x 64] @ [64 x 192] --------------------
// Wave = 16 nodes. 12 output tiles (4 y, 4 z, 4 r) x 2 K-halves = 24 MFMA.
// A-frag: node = lane&15, k = (lane>>4)*8 + j (+32 for half 1).
// D tile: col = lane&15, row(node) = (lane>>4)*4 + reg.
// LDS W: [192][64] bf16, XOR-swizzled (byte ^= ((row&7)<<4)) both sides.
template <bool RELU>
__global__ __launch_bounds__(256) void transformM(
    const float* __restrict__ h, const unsigned short* __restrict__ WtP,
    const float* __restrict__ b, unsigned* __restrict__ yzp,
    float* __restrict__ agg, int n) {
  __shared__ uint4 ldsW4[1536];  // 24 KB
  char* ldsW = (char*)ldsW4;
  int t = threadIdx.x;
  const uint4* wg = (const uint4*)WtP;
#pragma unroll
  for (int i = 0; i < 6; ++i) {
    int idx = t + i * 256;
    int off = idx * 16;
    int dst = off ^ (((off >> 7) & 7) << 4);
    *(uint4*)(ldsW + dst) = wg[idx];
  }
  __syncthreads();
  int wid = t >> 6, lane = t & 63;
  int n0 = blockIdx.x * 64 + wid * 16;
  if (n0 >= n) return;
  int arow = lane & 15, g = lane >> 4;
  int nodeA = min(n0 + arow, n - 1);
  const float* hp = h + (size_t)nodeA * 64 + g * 8;
  float4 f0 = *(const float4*)(hp);
  float4 f1 = *(const float4*)(hp + 4);
  float4 f2 = *(const float4*)(hp + 32);
  float4 f3 = *(const float4*)(hp + 36);
  if (RELU) {
    f0.x = fmaxf(f0.x, 0.f); f0.y = fmaxf(f0.y, 0.f); f0.z = fmaxf(f0.z, 0.f); f0.w = fmaxf(f0.w, 0.f);
    f1.x = fmaxf(f1.x, 0.f); f1.y = fmaxf(f1.y, 0.f); f1.z = fmaxf(f1.z, 0.f); f1.w = fmaxf(f1.w, 0.f);
    f2.x = fmaxf(f2.x, 0.f); f2.y = fmaxf(f2.y, 0.f); f2.z = fmaxf(f2.z, 0.f); f2.w = fmaxf(f2.w, 0.f);
    f3.x = fmaxf(f3.x, 0.f); f3.y = fmaxf(f3.y, 0.f); f3.z = fmaxf(f3.z, 0.f); f3.w = fmaxf(f3.w, 0.f);
  }
  s16x8 a0, a1;
  a0[0] = (short)f2bf(f0.x); a0[1] = (short)f2bf(f0.y);
  a0[2] = (short)f2bf(f0.z); a0[3] = (short)f2bf(f0.w);
  a0[4] = (short)f2bf(f1.x); a0[5] = (short)f2bf(f1.y);
  a0[6] = (short)f2bf(f1.z); a0[7] = (short)f2bf(f1.w);
  a1[0] = (short)f2bf(f2.x); a1[1] = (short)f2bf(f2.y);
  a1[2] = (short)f2bf(f2.z); a1[3] = (short)f2bf(f2.w);
  a1[4] = (short)f2bf(f3.x); a1[5] = (short)f2bf(f3.y);
  a1[6] = (short)f2bf(f3.z); a1[7] = (short)f2bf(f3.w);

  f32x4 acc[12];
#pragma unroll
  for (int tt = 0; tt < 12; ++tt) acc[tt] = (f32x4){0.f, 0.f, 0.f, 0.f};
#pragma unroll
  for (int tt = 0; tt < 12; ++tt) {
    int r0 = tt * 16 + arow;  // B^T row = output index
    int sw = (r0 & 7) << 4;
    int byte0 = (r0 * 128 + g * 16) ^ sw;
    int byte1 = (r0 * 128 + 64 + g * 16) ^ sw;
    s16x8 b0 = *(const s16x8*)(ldsW + byte0);
    s16x8 b1 = *(const s16x8*)(ldsW + byte1);
    acc[tt] = __builtin_amdgcn_mfma_f32_16x16x32_bf16(a0, b0, acc[tt], 0, 0, 0);
    acc[tt] = __builtin_amdgcn_mfma_f32_16x16x32_bf16(a1, b1, acc[tt], 0, 0, 0);
  }
  // epilogue: tiles 0-3 = y, 4-7 = z, 8-11 = r
  int c = lane & 15;
#pragma unroll
  for (int tt = 0; tt < 4; ++tt) {
    float bb = b[tt * 16 + c];
#pragma unroll
    for (int r2 = 0; r2 < 4; ++r2) {
      int nd = n0 + g * 4 + r2;
      if (nd < n) {
        yzp[(size_t)nd * 64 + tt * 16 + c] = packYZ(acc[tt][r2], acc[tt + 4][r2]);
        agg[(size_t)nd * 64 + tt * 16 + c] = acc[tt + 8][r2] + bb;
      }
    }
  }
}

// Layer 3 transform: lanes 0..3 hold the 4 classes for y,z,r.
__global__ __launch_bounds__(256) void transform3(
    const float* __restrict__ h, const float* __restrict__ Wm,
    const float* __restrict__ Bm, const float* __restrict__ Wr,
    const float* __restrict__ b, unsigned* __restrict__ yz3p,
    float* __restrict__ agg3, int n) {
  int wave = (blockIdx.x * 256 + threadIdx.x) >> 6;
  int lane = threadIdx.x & 63;
  int nb = wave << 2;
  if (nb >= n) return;
  int o = lane & 3;
  float hv[4];
#pragma unroll
  for (int j = 0; j < 4; ++j) {
    int nn = nb + j;
    float v = (nn < n) ? h[(size_t)nn * D + lane] : 0.f;
    hv[j] = fmaxf(v, 0.f);
  }
  float accY[4] = {0.f, 0.f, 0.f, 0.f};
  float accZ[4] = {0.f, 0.f, 0.f, 0.f};
  float accR[4] = {0.f, 0.f, 0.f, 0.f};
#pragma unroll 8
  for (int k = 0; k < D; ++k) {
    float wm = Wm[k * 4 + o];
    float wb = Bm[k * 4 + o];
    float wr = Wr[k * 4 + o];
#pragma unroll
    for (int j = 0; j < 4; ++j) {
      float hk = __shfl(hv[j], k, 64);
      accY[j] = fmaf(hk, wm, accY[j]);
      accZ[j] = fmaf(hk, wb, accZ[j]);
      accR[j] = fmaf(hk, wr, accR[j]);
    }
  }
  if (lane < 4) {
    float bb = b[o];
#pragma unroll
    for (int j = 0; j < 4; ++j) {
      int nn = nb + j;
      if (nn >= n) break;
      yz3p[(size_t)nn * 4 + o] = packYZ(accY[j], accZ[j]);
      agg3[(size_t)nn * 4 + o] = accR[j] + bb;
    }
  }
}

// --------- CSR build: histA -> scanCols -> scatterC -> placeK ---------------
// Deterministic counting sort; NO global atomics anywhere.

__global__ __launch_bounds__(256) void histA(const int* __restrict__ ei,
                                             int* __restrict__ hist, int ne) {
  __shared__ int h[NBUCK];
  int t = threadIdx.x;
  for (int i = t; i < NBUCK; i += 256) h[i] = 0;
  __syncthreads();
  int chunk = (ne + PART_BLOCKS - 1) / PART_BLOCKS;
  int e0 = blockIdx.x * chunk;
  int e1 = min(ne, e0 + chunk);
  for (int e = e0 + t; e < e1; e += 256)
    atomicAdd(&h[ei[ne + e] >> 8], 1);
  __syncthreads();
  for (int i = t; i < NBUCK; i += 256) hist[blockIdx.x * NBUCK + i] = h[i];
}

__global__ __launch_bounds__(256) void scanCols(int* __restrict__ hist,
                                                int* __restrict__ gTotal) {
  __shared__ int wsum[4];
  int b = blockIdx.x;
  int t = threadIdx.x;
  int v = hist[t * NBUCK + b];
  int lane = t & 63, wid = t >> 6;
  int inc = v;
#pragma unroll
  for (int d = 1; d < 64; d <<= 1) {
    int u = __shfl_up(inc, d, 64);
    if (lane >= d) inc += u;
  }
  if (lane == 63) wsum[wid] = inc;
  __syncthreads();
  if (t == 0) {
    int a = 0;
#pragma unroll
    for (int w = 0; w < 4; ++w) { int tmp = wsum[w]; wsum[w] = a; a += tmp; }
  }
  __syncthreads();
  int excl = wsum[wid] + inc - v;
  hist[t * NBUCK + b] = b * CAPB + excl;
  if (t == 255) gTotal[b] = excl + v;
}

__global__ __launch_bounds__(256) void scatterC(
    const int* __restrict__ ei, const float* __restrict__ ea,
    const int* __restrict__ baseArr, uint2* __restrict__ edgesP, int ne) {
  __shared__ int cnt[NBUCK];
  __shared__ int lbase[NBUCK];
  int t = threadIdx.x;
  for (int i = t; i < NBUCK; i += 256) {
    cnt[i] = 0;
    lbase[i] = baseArr[blockIdx.x * NBUCK + i];
  }
  __syncthreads();
  int chunk = (ne + PART_BLOCKS - 1) / PART_BLOCKS;
  int e0 = blockIdx.x * chunk;
  int e1 = min(ne, e0 + chunk);
  for (int e = e0 + t; e < e1; e += 256) {
    unsigned s = (unsigned)ei[e];
    int dd = ei[ne + e];
    unsigned abits = __float_as_uint(ea[e]);
    int bk = dd >> 8;
    int pos = atomicAdd(&cnt[bk], 1);
    edgesP[lbase[bk] + pos] = make_uint2(s | ((unsigned)(dd & 255) << 20), abits);
  }
}

__global__ __launch_bounds__(256) void placeK(
    const uint2* __restrict__ edgesP, const int* __restrict__ gTotal,
    uint2* __restrict__ edgeS, int* __restrict__ offS, int* __restrict__ offE,
    int n) {
  __shared__ int deg[256];
  __shared__ int cur[256];
  __shared__ int wsum[4];
  int b = blockIdx.x;
  int t = threadIdx.x;
  int base = b * CAPB;
  int cnt = gTotal[b];
  int n0 = b << 8;
  int nn = min(256, n - n0);
  deg[t] = 0;
  __syncthreads();
  for (int i = t; i < cnt; i += 256)
    atomicAdd(&deg[edgesP[base + i].x >> 20], 1);
  __syncthreads();
  int v = deg[t];
  int lane = t & 63, wid = t >> 6;
  int inc = v;
#pragma unroll
  for (int d2 = 1; d2 < 64; d2 <<= 1) {
    int u = __shfl_up(inc, d2, 64);
    if (lane >= d2) inc += u;
  }
  if (lane == 63) wsum[wid] = inc;
  __syncthreads();
  if (t == 0) {
    int a = 0;
#pragma unroll
    for (int w = 0; w < 4; ++w) { int tmp = wsum[w]; wsum[w] = a; a += tmp; }
  }
  __syncthreads();
  int excl = wsum[wid] + inc - v;
  cur[t] = excl;
  if (t < nn) {
    offS[n0 + t] = base + excl;
    offE[n0 + t] = base + excl + v;
  }
  __syncthreads();
  for (int i = t; i < cnt; i += 256) {
    uint2 ent = edgesP[base + i];
    int dl = ent.x >> 20;
    int slot = base + atomicAdd(&cur[dl], 1);
    edgeS[slot] = make_uint2(ent.x & 0xFFFFFu, ent.y);
  }
}

// ---------------- gather-aggregate (conflict-free, one write per node) ------

__global__ __launch_bounds__(256) void gather64(
    const int* __restrict__ offS, const int* __restrict__ offE,
    const uint2* __restrict__ edgeS, const unsigned* __restrict__ yzp,
    float* __restrict__ agg, int n) {
  int node = (blockIdx.x * 256 + threadIdx.x) >> 6;
  int lane = threadIdx.x & 63;
  if (node >= n) return;
  int j = offS[node];
  int jend = offE[node];
  float acc = agg[(size_t)node * 64 + lane];
#pragma unroll 1
  for (; j + 3 < jend; j += 4) {
    uint2 e0 = edgeS[j], e1 = edgeS[j + 1], e2 = edgeS[j + 2], e3 = edgeS[j + 3];
    unsigned p0 = yzp[(size_t)e0.x * 64 + lane];
    unsigned p1 = yzp[(size_t)e1.x * 64 + lane];
    unsigned p2 = yzp[(size_t)e2.x * 64 + lane];
    unsigned p3 = yzp[(size_t)e3.x * 64 + lane];
    acc += fmaf(__uint_as_float(e0.y), bfLo(p0), bfHi(p0));
    acc += fmaf(__uint_as_float(e1.y), bfLo(p1), bfHi(p1));
    acc += fmaf(__uint_as_float(e2.y), bfLo(p2), bfHi(p2));
    acc += fmaf(__uint_as_float(e3.y), bfLo(p3), bfHi(p3));
  }
#pragma unroll 1
  for (; j < jend; ++j) {
    uint2 e0 = edgeS[j];
    unsigned p0 = yzp[(size_t)e0.x * 64 + lane];
    acc += fmaf(__uint_as_float(e0.y), bfLo(p0), bfHi(p0));
  }
  agg[(size_t)node * 64 + lane] = acc;
}

__global__ __launch_bounds__(256) void gather4_logsm(
    const int* __restrict__ offS, const int* __restrict__ offE,
    const uint2* __restrict__ edgeS, const unsigned* __restrict__ yz3p,
    const float* __restrict__ agg3, float* __restrict__ out, int n) {
  int idx = blockIdx.x * 256 + threadIdx.x;
  int node = idx >> 2;
  int o = idx & 3;
  if (node >= n) return;
  int j = offS[node];
  int jend = offE[node];
  float acc = agg3[(size_t)node * 4 + o];
#pragma unroll 1
  for (; j < jend; ++j) {
    uint2 ed = edgeS[j];
    unsigned p = yz3p[(size_t)ed.x * 4 + o];
    acc += fmaf(__uint_as_float(ed.y), bfLo(p), bfHi(p));
  }
  float m = acc;
  m = fmaxf(m, __shfl_xor(m, 1, 4));
  m = fmaxf(m, __shfl_xor(m, 2, 4));
  float s = expf(acc - m);
  s += __shfl_xor(s, 1, 4);
  s += __shfl_xor(s, 2, 4);
  out[(size_t)node * 4 + o] = acc - m - logf(s);
}

// ---------------- launch -----------------------------------------------------

extern "C" void kernel_launch(void* const* d_in, const int* in_sizes, int n_in,
                              void* d_out, int out_size, void* d_ws, size_t ws_size,
                              hipStream_t stream) {
  const float* x = (const float*)d_in[0];
  const int* ei = (const int*)d_in[1];
  const float* ea = (const float*)d_in[2];
  const float* We1 = (const float*)d_in[3];
  const float* be1 = (const float*)d_in[4];
  const float* Wr1 = (const float*)d_in[5];
  const float* b1 = (const float*)d_in[6];
  const float* We2 = (const float*)d_in[7];
  const float* be2 = (const float*)d_in[8];
  const float* Wr2 = (const float*)d_in[9];
  const float* b2 = (const float*)d_in[10];
  const float* We3 = (const float*)d_in[11];
  const float* be3 = (const float*)d_in[12];
  const float* Wr3 = (const float*)d_in[13];
  const float* b3 = (const float*)d_in[14];

  const int N = in_sizes[0] / D;  // 100000
  const int E = in_sizes[2];      // 1600000
  const size_t EREG = (size_t)NBUCK * CAPB;  // padded CSR storage (~1.86M entries)

  // ws layout. edgesP aliases agg2; agg3/yz3p alias agg1.
  char* ws = (char*)d_ws;
  uint2* edgeS = (uint2*)ws;                                 // EREG * 8B
  unsigned* yzp = (unsigned*)(ws + EREG * 8);                // N*64 * 4B
  float* agg1 = (float*)((char*)yzp + (size_t)N * 64 * 4);   // N*64
  float* agg2 = agg1 + (size_t)N * 64;                       // N*64
  int* offS = (int*)(agg2 + (size_t)N * 64);                 // N
  int* offE = offS + N;                                      // N
  int* gTotal = offE + N;                                    // NBUCK
  int* hist = gTotal + NBUCK;                                // PART_BLOCKS*NBUCK
  unsigned short* Wt = (unsigned short*)(hist + PART_BLOCKS * NBUCK);  // 2*12288 bf16
  uint2* edgesP = (uint2*)agg2;                              // alias
  float* agg3 = agg1;                                        // alias
  unsigned* yz3p = (unsigned*)(agg1 + (size_t)N * 4);        // alias
  float* out = (float*)d_out;

  int waves = (N + 3) / 4;
  int tblocks = (waves + 3) / 4;           // transform3: 4 waves/block
  int tblocksM = (N + 63) / 64;            // transformM: 64 nodes/block
  int g64blocks = (int)(((long long)N * 64 + 255) / 256);
  int g4blocks = (int)(((long long)N * 4 + 255) / 256);

  // ---- weight prep + CSR build (deterministic counting sort) ----
  wprep<<<2, 256, 0, stream>>>(We1, be1, Wr1, We2, be2, Wr2, Wt);
  histA<<<PART_BLOCKS, 256, 0, stream>>>(ei, hist, E);
  scanCols<<<NBUCK, 256, 0, stream>>>(hist, gTotal);
  scatterC<<<PART_BLOCKS, 256, 0, stream>>>(ei, ea, hist, edgesP, E);
  placeK<<<NBUCK, 256, 0, stream>>>(edgesP, gTotal, edgeS, offS, offE, N);

  // ---- Layer 1: x -> agg1 ----
  transformM<false><<<tblocksM, 256, 0, stream>>>(x, Wt, b1, yzp, agg1, N);
  gather64<<<g64blocks, 256, 0, stream>>>(offS, offE, edgeS, yzp, agg1, N);
  // ---- Layer 2: relu(agg1) -> agg2 ----
  transformM<true><<<tblocksM, 256, 0, stream>>>(agg1, Wt + 12288, b2, yzp, agg2, N);
  gather64<<<g64blocks, 256, 0, stream>>>(offS, offE, edgeS, yzp, agg2, N);
  // ---- Layer 3: relu(agg2) -> out (fused log_softmax) ----
  transform3<<<tblocks, 256, 0, stream>>>(agg2, We3, be3, Wr3, b3, yz3p, agg3, N);
  gather4_logsm<<<g4blocks, 256, 0, stream>>>(offS, offE, edgeS, yz3p, agg3, out, N);
}

// Round 8
// 357.981 us; speedup vs baseline: 3.3656x; 1.1661x over previous
//
#include <hip/hip_runtime.h>
#include <math.h>

#define D 64
#define NBUCK 392         // buckets of 256 nodes: bucket = dst >> 8 (392*256=100352)
#define CAPB 4736         // fixed bucket capacity: mean 4096 + 10 sigma, 8-entry aligned
#define PART_BLOCKS 256

typedef __attribute__((ext_vector_type(4))) float f32x4;
typedef __attribute__((ext_vector_type(8))) short s16x8;

// ---- bf16 pack helpers (RNE) ----
__device__ __forceinline__ unsigned short f2bf(float f) {
  unsigned u = __float_as_uint(f);
  unsigned r = (u + 0x7fff + ((u >> 16) & 1)) >> 16;
  return (unsigned short)r;
}
__device__ __forceinline__ float bfLo(unsigned p) { return __uint_as_float(p << 16); }
__device__ __forceinline__ float bfHi(unsigned p) { return __uint_as_float(p & 0xffff0000u); }
__device__ __forceinline__ unsigned packYZ(float y, float z) {
  return (unsigned)f2bf(y) | ((unsigned)f2bf(z) << 16);
}

// ------- weight prep ---------------------------------------------------------
// blocks 0,1: Wt[l] = bf16 [192][64], rows = [Wm|Bm|Wr]^T for layers 1,2.
// block 2:    Wt3   = bf16 [16][64],  rows = [We3|be3|Wr3|0]^T.

__global__ void wprep(const float* __restrict__ We1, const float* __restrict__ be1,
                      const float* __restrict__ Wr1, const float* __restrict__ We2,
                      const float* __restrict__ be2, const float* __restrict__ Wr2,
                      const float* __restrict__ We3, const float* __restrict__ be3,
                      const float* __restrict__ Wr3, unsigned short* __restrict__ Wt) {
  int l = blockIdx.x;
  if (l == 2) {
    unsigned short* Wt3 = Wt + 24576;
    for (int idx = threadIdx.x; idx < 1024; idx += 256) {
      int r = idx >> 6, k = idx & 63;
      int sel = r >> 2, o = r & 3;
      float v = (sel == 0) ? We3[k * 4 + o]
              : (sel == 1) ? be3[k * 4 + o]
              : (sel == 2) ? Wr3[k * 4 + o] : 0.f;
      Wt3[idx] = f2bf(v);
    }
    return;
  }
  const float* We = l ? We2 : We1;
  const float* be = l ? be2 : be1;
  const float* Wr = l ? Wr2 : Wr1;
  for (int idx = threadIdx.x; idx < 12288; idx += 256) {
    int r = idx >> 6, k = idx & 63;
    int sel = r >> 6, o = r & 63;
    float v = (sel == 0) ? We[k * 64 + o] : (sel == 1) ? be[k * 64 + o] : Wr[k * 64 + o];
    Wt[l * 12288 + idx] = f2bf(v);
  }
}

// ---------------- MFMA transform: [n x 64] @ [64 x 192] --------------------
// Wave = 16 nodes. 12 output tiles (4 y, 4 z, 4 r) x 2 K-halves = 24 MFMA.
// A-frag: node = lane&15, k = (lane>>4)*8 + j (+32 for half 1).
// D tile: col = lane&15, row(node) = (lane>>4)*4 + reg.
// LDS W: [192][64] bf16, XOR-swizzled (byte ^= ((row&7)<<4)) both sides.
template <bool RELU>
__global__ __launch_bounds__(256) void transformM(
    const float* __restrict__ h, const unsigned short* __restrict__ WtP,
    const float* __restrict__ b, unsigned* __restrict__ yzp,
    float* __restrict__ agg, int n) {
  __shared__ uint4 ldsW4[1536];  // 24 KB
  char* ldsW = (char*)ldsW4;
  int t = threadIdx.x;
  const uint4* wg = (const uint4*)WtP;
#pragma unroll
  for (int i = 0; i < 6; ++i) {
    int idx = t + i * 256;
    int off = idx * 16;
    int dst = off ^ (((off >> 7) & 7) << 4);
    *(uint4*)(ldsW + dst) = wg[idx];
  }
  __syncthreads();
  int wid = t >> 6, lane = t & 63;
  int n0 = blockIdx.x * 64 + wid * 16;
  if (n0 >= n) return;
  int arow = lane & 15, g = lane >> 4;
  int nodeA = min(n0 + arow, n - 1);
  const float* hp = h + (size_t)nodeA * 64 + g * 8;
  float4 f0 = *(const float4*)(hp);
  float4 f1 = *(const float4*)(hp + 4);
  float4 f2 = *(const float4*)(hp + 32);
  float4 f3 = *(const float4*)(hp + 36);
  if (RELU) {
    f0.x = fmaxf(f0.x, 0.f); f0.y = fmaxf(f0.y, 0.f); f0.z = fmaxf(f0.z, 0.f); f0.w = fmaxf(f0.w, 0.f);
    f1.x = fmaxf(f1.x, 0.f); f1.y = fmaxf(f1.y, 0.f); f1.z = fmaxf(f1.z, 0.f); f1.w = fmaxf(f1.w, 0.f);
    f2.x = fmaxf(f2.x, 0.f); f2.y = fmaxf(f2.y, 0.f); f2.z = fmaxf(f2.z, 0.f); f2.w = fmaxf(f2.w, 0.f);
    f3.x = fmaxf(f3.x, 0.f); f3.y = fmaxf(f3.y, 0.f); f3.z = fmaxf(f3.z, 0.f); f3.w = fmaxf(f3.w, 0.f);
  }
  s16x8 a0, a1;
  a0[0] = (short)f2bf(f0.x); a0[1] = (short)f2bf(f0.y);
  a0[2] = (short)f2bf(f0.z); a0[3] = (short)f2bf(f0.w);
  a0[4] = (short)f2bf(f1.x); a0[5] = (short)f2bf(f1.y);
  a0[6] = (short)f2bf(f1.z); a0[7] = (short)f2bf(f1.w);
  a1[0] = (short)f2bf(f2.x); a1[1] = (short)f2bf(f2.y);
  a1[2] = (short)f2bf(f2.z); a1[3] = (short)f2bf(f2.w);
  a1[4] = (short)f2bf(f3.x); a1[5] = (short)f2bf(f3.y);
  a1[6] = (short)f2bf(f3.z); a1[7] = (short)f2bf(f3.w);

  f32x4 acc[12];
#pragma unroll
  for (int tt = 0; tt < 12; ++tt) acc[tt] = (f32x4){0.f, 0.f, 0.f, 0.f};
#pragma unroll
  for (int tt = 0; tt < 12; ++tt) {
    int r0 = tt * 16 + arow;  // B^T row = output index
    int sw = (r0 & 7) << 4;
    int byte0 = (r0 * 128 + g * 16) ^ sw;
    int byte1 = (r0 * 128 + 64 + g * 16) ^ sw;
    s16x8 b0 = *(const s16x8*)(ldsW + byte0);
    s16x8 b1 = *(const s16x8*)(ldsW + byte1);
    acc[tt] = __builtin_amdgcn_mfma_f32_16x16x32_bf16(a0, b0, acc[tt], 0, 0, 0);
    acc[tt] = __builtin_amdgcn_mfma_f32_16x16x32_bf16(a1, b1, acc[tt], 0, 0, 0);
  }
  // epilogue: tiles 0-3 = y, 4-7 = z, 8-11 = r
  int c = lane & 15;
#pragma unroll
  for (int tt = 0; tt < 4; ++tt) {
    float bb = b[tt * 16 + c];
#pragma unroll
    for (int r2 = 0; r2 < 4; ++r2) {
      int nd = n0 + g * 4 + r2;
      if (nd < n) {
        yzp[(size_t)nd * 64 + tt * 16 + c] = packYZ(acc[tt][r2], acc[tt + 4][r2]);
        agg[(size_t)nd * 64 + tt * 16 + c] = acc[tt + 8][r2] + bb;
      }
    }
  }
}

// ------- MFMA layer-3 transform: [n x 64] @ [64 x 16] -----------------------
// Wave = 16 nodes, ONE output tile (cols: 0-3=y, 4-7=z, 8-11=r, 12-15=pad),
// 2 MFMA (K-halves). B-frags straight from global (2KB, L2-hot). Epilogue:
// shfl_xor(4) brings z to the y-lane, shfl_xor(8) brings r.
__global__ __launch_bounds__(256) void transform3M(
    const float* __restrict__ h, const unsigned short* __restrict__ Wt3,
    const float* __restrict__ b, unsigned* __restrict__ yz3p,
    float* __restrict__ agg3, int n) {
  int t = threadIdx.x;
  int wid = t >> 6, lane = t & 63;
  int n0 = blockIdx.x * 64 + wid * 16;
  if (n0 >= n) return;
  int arow = lane & 15, g = lane >> 4;
  int nodeA = min(n0 + arow, n - 1);
  const float* hp = h + (size_t)nodeA * 64 + g * 8;
  float4 f0 = *(const float4*)(hp);
  float4 f1 = *(const float4*)(hp + 4);
  float4 f2 = *(const float4*)(hp + 32);
  float4 f3 = *(const float4*)(hp + 36);
  f0.x = fmaxf(f0.x, 0.f); f0.y = fmaxf(f0.y, 0.f); f0.z = fmaxf(f0.z, 0.f); f0.w = fmaxf(f0.w, 0.f);
  f1.x = fmaxf(f1.x, 0.f); f1.y = fmaxf(f1.y, 0.f); f1.z = fmaxf(f1.z, 0.f); f1.w = fmaxf(f1.w, 0.f);
  f2.x = fmaxf(f2.x, 0.f); f2.y = fmaxf(f2.y, 0.f); f2.z = fmaxf(f2.z, 0.f); f2.w = fmaxf(f2.w, 0.f);
  f3.x = fmaxf(f3.x, 0.f); f3.y = fmaxf(f3.y, 0.f); f3.z = fmaxf(f3.z, 0.f); f3.w = fmaxf(f3.w, 0.f);
  s16x8 a0, a1;
  a0[0] = (short)f2bf(f0.x); a0[1] = (short)f2bf(f0.y);
  a0[2] = (short)f2bf(f0.z); a0[3] = (short)f2bf(f0.w);
  a0[4] = (short)f2bf(f1.x); a0[5] = (short)f2bf(f1.y);
  a0[6] = (short)f2bf(f1.z); a0[7] = (short)f2bf(f1.w);
  a1[0] = (short)f2bf(f2.x); a1[1] = (short)f2bf(f2.y);
  a1[2] = (short)f2bf(f2.z); a1[3] = (short)f2bf(f2.w);
  a1[4] = (short)f2bf(f3.x); a1[5] = (short)f2bf(f3.y);
  a1[6] = (short)f2bf(f3.z); a1[7] = (short)f2bf(f3.w);
  // B-frag: output col = lane&15 = row of Wt3; k = g*8 + j (+32 for half 1)
  s16x8 b0 = *(const s16x8*)(Wt3 + arow * 64 + g * 8);
  s16x8 b1 = *(const s16x8*)(Wt3 + arow * 64 + 32 + g * 8);
  f32x4 acc = (f32x4){0.f, 0.f, 0.f, 0.f};
  acc = __builtin_amdgcn_mfma_f32_16x16x32_bf16(a0, b0, acc, 0, 0, 0);
  acc = __builtin_amdgcn_mfma_f32_16x16x32_bf16(a1, b1, acc, 0, 0, 0);
  float bb = (arow < 4) ? b[arow] : 0.f;
#pragma unroll
  for (int r2 = 0; r2 < 4; ++r2) {
    float zv = __shfl_xor(acc[r2], 4, 64);
    float rv = __shfl_xor(acc[r2], 8, 64);
    int nd = n0 + g * 4 + r2;
    if (arow < 4 && nd < n) {
      yz3p[(size_t)nd * 4 + arow] = packYZ(acc[r2], zv);
      agg3[(size_t)nd * 4 + arow] = rv + bb;
    }
  }
}

// --------- CSR build: histA -> scanCols -> scatterC -> placeK ---------------
// Deterministic counting sort; NO global atomics anywhere.

__global__ __launch_bounds__(256) void histA(const int* __restrict__ ei,
                                             int* __restrict__ hist, int ne) {
  __shared__ int h[NBUCK];
  int t = threadIdx.x;
  for (int i = t; i < NBUCK; i += 256) h[i] = 0;
  __syncthreads();
  int chunk = (ne + PART_BLOCKS - 1) / PART_BLOCKS;
  int e0 = blockIdx.x * chunk;
  int e1 = min(ne, e0 + chunk);
  for (int e = e0 + t; e < e1; e += 256)
    atomicAdd(&h[ei[ne + e] >> 8], 1);
  __syncthreads();
  for (int i = t; i < NBUCK; i += 256) hist[blockIdx.x * NBUCK + i] = h[i];
}

__global__ __launch_bounds__(256) void scanCols(int* __restrict__ hist,
                                                int* __restrict__ gTotal) {
  __shared__ int wsum[4];
  int b = blockIdx.x;
  int t = threadIdx.x;
  int v = hist[t * NBUCK + b];
  int lane = t & 63, wid = t >> 6;
  int inc = v;
#pragma unroll
  for (int d = 1; d < 64; d <<= 1) {
    int u = __shfl_up(inc, d, 64);
    if (lane >= d) inc += u;
  }
  if (lane == 63) wsum[wid] = inc;
  __syncthreads();
  if (t == 0) {
    int a = 0;
#pragma unroll
    for (int w = 0; w < 4; ++w) { int tmp = wsum[w]; wsum[w] = a; a += tmp; }
  }
  __syncthreads();
  int excl = wsum[wid] + inc - v;
  hist[t * NBUCK + b] = b * CAPB + excl;
  if (t == 255) gTotal[b] = excl + v;
}

__global__ __launch_bounds__(256) void scatterC(
    const int* __restrict__ ei, const float* __restrict__ ea,
    const int* __restrict__ baseArr, uint2* __restrict__ edgesP, int ne) {
  __shared__ int cnt[NBUCK];
  __shared__ int lbase[NBUCK];
  int t = threadIdx.x;
  for (int i = t; i < NBUCK; i += 256) {
    cnt[i] = 0;
    lbase[i] = baseArr[blockIdx.x * NBUCK + i];
  }
  __syncthreads();
  int chunk = (ne + PART_BLOCKS - 1) / PART_BLOCKS;
  int e0 = blockIdx.x * chunk;
  int e1 = min(ne, e0 + chunk);
  for (int e = e0 + t; e < e1; e += 256) {
    unsigned s = (unsigned)ei[e];
    int dd = ei[ne + e];
    unsigned abits = __float_as_uint(ea[e]);
    int bk = dd >> 8;
    int pos = atomicAdd(&cnt[bk], 1);
    edgesP[lbase[bk] + pos] = make_uint2(s | ((unsigned)(dd & 255) << 20), abits);
  }
}

__global__ __launch_bounds__(256) void placeK(
    const uint2* __restrict__ edgesP, const int* __restrict__ gTotal,
    uint2* __restrict__ edgeS, int* __restrict__ offS, int* __restrict__ offE,
    int n) {
  __shared__ int deg[256];
  __shared__ int cur[256];
  __shared__ int wsum[4];
  int b = blockIdx.x;
  int t = threadIdx.x;
  int base = b * CAPB;
  int cnt = gTotal[b];
  int n0 = b << 8;
  int nn = min(256, n - n0);
  deg[t] = 0;
  __syncthreads();
  for (int i = t; i < cnt; i += 256)
    atomicAdd(&deg[edgesP[base + i].x >> 20], 1);
  __syncthreads();
  int v = deg[t];
  int lane = t & 63, wid = t >> 6;
  int inc = v;
#pragma unroll
  for (int d2 = 1; d2 < 64; d2 <<= 1) {
    int u = __shfl_up(inc, d2, 64);
    if (lane >= d2) inc += u;
  }
  if (lane == 63) wsum[wid] = inc;
  __syncthreads();
  if (t == 0) {
    int a = 0;
#pragma unroll
    for (int w = 0; w < 4; ++w) { int tmp = wsum[w]; wsum[w] = a; a += tmp; }
  }
  __syncthreads();
  int excl = wsum[wid] + inc - v;
  cur[t] = excl;
  if (t < nn) {
    offS[n0 + t] = base + excl;
    offE[n0 + t] = base + excl + v;
  }
  __syncthreads();
  for (int i = t; i < cnt; i += 256) {
    uint2 ent = edgesP[base + i];
    int dl = ent.x >> 20;
    int slot = base + atomicAdd(&cur[dl], 1);
    edgeS[slot] = make_uint2(ent.x & 0xFFFFFu, ent.y);
  }
}

// ---------------- gather-aggregate (conflict-free, one write per node) ------

__global__ __launch_bounds__(256) void gather64(
    const int* __restrict__ offS, const int* __restrict__ offE,
    const uint2* __restrict__ edgeS, const unsigned* __restrict__ yzp,
    float* __restrict__ agg, int n) {
  int node = (blockIdx.x * 256 + threadIdx.x) >> 6;
  int lane = threadIdx.x & 63;
  if (node >= n) return;
  int j = offS[node];
  int jend = offE[node];
  float acc = agg[(size_t)node * 64 + lane];
#pragma unroll 1
  for (; j + 3 < jend; j += 4) {
    uint2 e0 = edgeS[j], e1 = edgeS[j + 1], e2 = edgeS[j + 2], e3 = edgeS[j + 3];
    unsigned p0 = yzp[(size_t)e0.x * 64 + lane];
    unsigned p1 = yzp[(size_t)e1.x * 64 + lane];
    unsigned p2 = yzp[(size_t)e2.x * 64 + lane];
    unsigned p3 = yzp[(size_t)e3.x * 64 + lane];
    acc += fmaf(__uint_as_float(e0.y), bfLo(p0), bfHi(p0));
    acc += fmaf(__uint_as_float(e1.y), bfLo(p1), bfHi(p1));
    acc += fmaf(__uint_as_float(e2.y), bfLo(p2), bfHi(p2));
    acc += fmaf(__uint_as_float(e3.y), bfLo(p3), bfHi(p3));
  }
#pragma unroll 1
  for (; j < jend; ++j) {
    uint2 e0 = edgeS[j];
    unsigned p0 = yzp[(size_t)e0.x * 64 + lane];
    acc += fmaf(__uint_as_float(e0.y), bfLo(p0), bfHi(p0));
  }
  agg[(size_t)node * 64 + lane] = acc;
}

__global__ __launch_bounds__(256) void gather4_logsm(
    const int* __restrict__ offS, const int* __restrict__ offE,
    const uint2* __restrict__ edgeS, const unsigned* __restrict__ yz3p,
    const float* __restrict__ agg3, float* __restrict__ out, int n) {
  int idx = blockIdx.x * 256 + threadIdx.x;
  int node = idx >> 2;
  int o = idx & 3;
  if (node >= n) return;
  int j = offS[node];
  int jend = offE[node];
  float acc = agg3[(size_t)node * 4 + o];
#pragma unroll 1
  for (; j < jend; ++j) {
    uint2 ed = edgeS[j];
    unsigned p = yz3p[(size_t)ed.x * 4 + o];
    acc += fmaf(__uint_as_float(ed.y), bfLo(p), bfHi(p));
  }
  float m = acc;
  m = fmaxf(m, __shfl_xor(m, 1, 4));
  m = fmaxf(m, __shfl_xor(m, 2, 4));
  float s = expf(acc - m);
  s += __shfl_xor(s, 1, 4);
  s += __shfl_xor(s, 2, 4);
  out[(size_t)node * 4 + o] = acc - m - logf(s);
}

// ---------------- launch -----------------------------------------------------

extern "C" void kernel_launch(void* const* d_in, const int* in_sizes, int n_in,
                              void* d_out, int out_size, void* d_ws, size_t ws_size,
                              hipStream_t stream) {
  const float* x = (const float*)d_in[0];
  const int* ei = (const int*)d_in[1];
  const float* ea = (const float*)d_in[2];
  const float* We1 = (const float*)d_in[3];
  const float* be1 = (const float*)d_in[4];
  const float* Wr1 = (const float*)d_in[5];
  const float* b1 = (const float*)d_in[6];
  const float* We2 = (const float*)d_in[7];
  const float* be2 = (const float*)d_in[8];
  const float* Wr2 = (const float*)d_in[9];
  const float* b2 = (const float*)d_in[10];
  const float* We3 = (const float*)d_in[11];
  const float* be3 = (const float*)d_in[12];
  const float* Wr3 = (const float*)d_in[13];
  const float* b3 = (const float*)d_in[14];

  const int N = in_sizes[0] / D;  // 100000
  const int E = in_sizes[2];      // 1600000
  const size_t EREG = (size_t)NBUCK * CAPB;  // padded CSR storage (~1.86M entries)

  // ws layout. edgesP aliases agg2; agg3/yz3p alias agg1.
  char* ws = (char*)d_ws;
  uint2* edgeS = (uint2*)ws;                                 // EREG * 8B
  unsigned* yzp = (unsigned*)(ws + EREG * 8);                // N*64 * 4B
  float* agg1 = (float*)((char*)yzp + (size_t)N * 64 * 4);   // N*64
  float* agg2 = agg1 + (size_t)N * 64;                       // N*64
  int* offS = (int*)(agg2 + (size_t)N * 64);                 // N
  int* offE = offS + N;                                      // N
  int* gTotal = offE + N;                                    // NBUCK
  int* hist = gTotal + NBUCK;                                // PART_BLOCKS*NBUCK
  unsigned short* Wt = (unsigned short*)(hist + PART_BLOCKS * NBUCK);  // 2*12288+1024 bf16
  uint2* edgesP = (uint2*)agg2;                              // alias
  float* agg3 = agg1;                                        // alias
  unsigned* yz3p = (unsigned*)(agg1 + (size_t)N * 4);        // alias
  float* out = (float*)d_out;

  int tblocksM = (N + 63) / 64;            // transformM/transform3M: 64 nodes/block
  int g64blocks = (int)(((long long)N * 64 + 255) / 256);
  int g4blocks = (int)(((long long)N * 4 + 255) / 256);

  // ---- weight prep + CSR build (deterministic counting sort) ----
  wprep<<<3, 256, 0, stream>>>(We1, be1, Wr1, We2, be2, Wr2, We3, be3, Wr3, Wt);
  histA<<<PART_BLOCKS, 256, 0, stream>>>(ei, hist, E);
  scanCols<<<NBUCK, 256, 0, stream>>>(hist, gTotal);
  scatterC<<<PART_BLOCKS, 256, 0, stream>>>(ei, ea, hist, edgesP, E);
  placeK<<<NBUCK, 256, 0, stream>>>(edgesP, gTotal, edgeS, offS, offE, N);

  // ---- Layer 1: x -> agg1 ----
  transformM<false><<<tblocksM, 256, 0, stream>>>(x, Wt, b1, yzp, agg1, N);
  gather64<<<g64blocks, 256, 0, stream>>>(offS, offE, edgeS, yzp, agg1, N);
  // ---- Layer 2: relu(agg1) -> agg2 ----
  transformM<true><<<tblocksM, 256, 0, stream>>>(agg1, Wt + 12288, b2, yzp, agg2, N);
  gather64<<<g64blocks, 256, 0, stream>>>(offS, offE, edgeS, yzp, agg2, N);
  // ---- Layer 3: relu(agg2) -> out (fused log_softmax) ----
  transform3M<<<tblocksM, 256, 0, stream>>>(agg2, Wt + 24576, b3, yz3p, agg3, N);
  gather4_logsm<<<g4blocks, 256, 0, stream>>>(offS, offE, edgeS, yz3p, agg3, out, N);
}

// Round 9
// 335.842 us; speedup vs baseline: 3.5875x; 1.0659x over previous
//
#include <hip/hip_runtime.h>
#include <math.h>

#define D 64
#define NBUCK 392         // buckets of 256 nodes: bucket = dst >> 8 (392*256=100352)
#define CAPB 4736         // fixed bucket capacity: mean 4096 + 10 sigma, 8-entry aligned
#define PART_BLOCKS 256

typedef __attribute__((ext_vector_type(4))) float f32x4;
typedef __attribute__((ext_vector_type(8))) short s16x8;

// ---- bf16 pack helpers (RNE) ----
__device__ __forceinline__ unsigned short f2bf(float f) {
  unsigned u = __float_as_uint(f);
  unsigned r = (u + 0x7fff + ((u >> 16) & 1)) >> 16;
  return (unsigned short)r;
}
__device__ __forceinline__ float bfLo(unsigned p) { return __uint_as_float(p << 16); }
__device__ __forceinline__ float bfHi(unsigned p) { return __uint_as_float(p & 0xffff0000u); }
__device__ __forceinline__ unsigned packYZ(float y, float z) {
  return (unsigned)f2bf(y) | ((unsigned)f2bf(z) << 16);
}

// ------- weight prep ---------------------------------------------------------
// blocks 0,1: Wt[l] = bf16 [192][64], rows = [Wm|Bm|Wr]^T for layers 1,2.
// block 2:    Wt3   = bf16 [16][64],  rows = [We3|be3|Wr3|0]^T.

__global__ void wprep(const float* __restrict__ We1, const float* __restrict__ be1,
                      const float* __restrict__ Wr1, const float* __restrict__ We2,
                      const float* __restrict__ be2, const float* __restrict__ Wr2,
                      const float* __restrict__ We3, const float* __restrict__ be3,
                      const float* __restrict__ Wr3, unsigned short* __restrict__ Wt) {
  int l = blockIdx.x;
  if (l == 2) {
    unsigned short* Wt3 = Wt + 24576;
    for (int idx = threadIdx.x; idx < 1024; idx += 256) {
      int r = idx >> 6, k = idx & 63;
      int sel = r >> 2, o = r & 3;
      float v = (sel == 0) ? We3[k * 4 + o]
              : (sel == 1) ? be3[k * 4 + o]
              : (sel == 2) ? Wr3[k * 4 + o] : 0.f;
      Wt3[idx] = f2bf(v);
    }
    return;
  }
  const float* We = l ? We2 : We1;
  const float* be = l ? be2 : be1;
  const float* Wr = l ? Wr2 : Wr1;
  for (int idx = threadIdx.x; idx < 12288; idx += 256) {
    int r = idx >> 6, k = idx & 63;
    int sel = r >> 6, o = r & 63;
    float v = (sel == 0) ? We[k * 64 + o] : (sel == 1) ? be[k * 64 + o] : Wr[k * 64 + o];
    Wt[l * 12288 + idx] = f2bf(v);
  }
}

// ---------------- MFMA transform: [n x 64] @ [64 x 192] --------------------
template <bool RELU>
__global__ __launch_bounds__(256) void transformM(
    const float* __restrict__ h, const unsigned short* __restrict__ WtP,
    const float* __restrict__ b, unsigned* __restrict__ yzp,
    float* __restrict__ agg, int n) {
  __shared__ uint4 ldsW4[1536];  // 24 KB
  char* ldsW = (char*)ldsW4;
  int t = threadIdx.x;
  const uint4* wg = (const uint4*)WtP;
#pragma unroll
  for (int i = 0; i < 6; ++i) {
    int idx = t + i * 256;
    int off = idx * 16;
    int dst = off ^ (((off >> 7) & 7) << 4);
    *(uint4*)(ldsW + dst) = wg[idx];
  }
  __syncthreads();
  int wid = t >> 6, lane = t & 63;
  int n0 = blockIdx.x * 64 + wid * 16;
  if (n0 >= n) return;
  int arow = lane & 15, g = lane >> 4;
  int nodeA = min(n0 + arow, n - 1);
  const float* hp = h + (size_t)nodeA * 64 + g * 8;
  float4 f0 = *(const float4*)(hp);
  float4 f1 = *(const float4*)(hp + 4);
  float4 f2 = *(const float4*)(hp + 32);
  float4 f3 = *(const float4*)(hp + 36);
  if (RELU) {
    f0.x = fmaxf(f0.x, 0.f); f0.y = fmaxf(f0.y, 0.f); f0.z = fmaxf(f0.z, 0.f); f0.w = fmaxf(f0.w, 0.f);
    f1.x = fmaxf(f1.x, 0.f); f1.y = fmaxf(f1.y, 0.f); f1.z = fmaxf(f1.z, 0.f); f1.w = fmaxf(f1.w, 0.f);
    f2.x = fmaxf(f2.x, 0.f); f2.y = fmaxf(f2.y, 0.f); f2.z = fmaxf(f2.z, 0.f); f2.w = fmaxf(f2.w, 0.f);
    f3.x = fmaxf(f3.x, 0.f); f3.y = fmaxf(f3.y, 0.f); f3.z = fmaxf(f3.z, 0.f); f3.w = fmaxf(f3.w, 0.f);
  }
  s16x8 a0, a1;
  a0[0] = (short)f2bf(f0.x); a0[1] = (short)f2bf(f0.y);
  a0[2] = (short)f2bf(f0.z); a0[3] = (short)f2bf(f0.w);
  a0[4] = (short)f2bf(f1.x); a0[5] = (short)f2bf(f1.y);
  a0[6] = (short)f2bf(f1.z); a0[7] = (short)f2bf(f1.w);
  a1[0] = (short)f2bf(f2.x); a1[1] = (short)f2bf(f2.y);
  a1[2] = (short)f2bf(f2.z); a1[3] = (short)f2bf(f2.w);
  a1[4] = (short)f2bf(f3.x); a1[5] = (short)f2bf(f3.y);
  a1[6] = (short)f2bf(f3.z); a1[7] = (short)f2bf(f3.w);

  f32x4 acc[12];
#pragma unroll
  for (int tt = 0; tt < 12; ++tt) acc[tt] = (f32x4){0.f, 0.f, 0.f, 0.f};
#pragma unroll
  for (int tt = 0; tt < 12; ++tt) {
    int r0 = tt * 16 + arow;  // B^T row = output index
    int sw = (r0 & 7) << 4;
    int byte0 = (r0 * 128 + g * 16) ^ sw;
    int byte1 = (r0 * 128 + 64 + g * 16) ^ sw;
    s16x8 b0 = *(const s16x8*)(ldsW + byte0);
    s16x8 b1 = *(const s16x8*)(ldsW + byte1);
    acc[tt] = __builtin_amdgcn_mfma_f32_16x16x32_bf16(a0, b0, acc[tt], 0, 0, 0);
    acc[tt] = __builtin_amdgcn_mfma_f32_16x16x32_bf16(a1, b1, acc[tt], 0, 0, 0);
  }
  // epilogue: tiles 0-3 = y, 4-7 = z, 8-11 = r
  int c = lane & 15;
#pragma unroll
  for (int tt = 0; tt < 4; ++tt) {
    float bb = b[tt * 16 + c];
#pragma unroll
    for (int r2 = 0; r2 < 4; ++r2) {
      int nd = n0 + g * 4 + r2;
      if (nd < n) {
        yzp[(size_t)nd * 64 + tt * 16 + c] = packYZ(acc[tt][r2], acc[tt + 4][r2]);
        agg[(size_t)nd * 64 + tt * 16 + c] = acc[tt + 8][r2] + bb;
      }
    }
  }
}

// ------- MFMA layer-3 transform: [n x 64] @ [64 x 16] -----------------------
__global__ __launch_bounds__(256) void transform3M(
    const float* __restrict__ h, const unsigned short* __restrict__ Wt3,
    const float* __restrict__ b, unsigned* __restrict__ yz3p,
    float* __restrict__ agg3, int n) {
  int t = threadIdx.x;
  int wid = t >> 6, lane = t & 63;
  int n0 = blockIdx.x * 64 + wid * 16;
  if (n0 >= n) return;
  int arow = lane & 15, g = lane >> 4;
  int nodeA = min(n0 + arow, n - 1);
  const float* hp = h + (size_t)nodeA * 64 + g * 8;
  float4 f0 = *(const float4*)(hp);
  float4 f1 = *(const float4*)(hp + 4);
  float4 f2 = *(const float4*)(hp + 32);
  float4 f3 = *(const float4*)(hp + 36);
  f0.x = fmaxf(f0.x, 0.f); f0.y = fmaxf(f0.y, 0.f); f0.z = fmaxf(f0.z, 0.f); f0.w = fmaxf(f0.w, 0.f);
  f1.x = fmaxf(f1.x, 0.f); f1.y = fmaxf(f1.y, 0.f); f1.z = fmaxf(f1.z, 0.f); f1.w = fmaxf(f1.w, 0.f);
  f2.x = fmaxf(f2.x, 0.f); f2.y = fmaxf(f2.y, 0.f); f2.z = fmaxf(f2.z, 0.f); f2.w = fmaxf(f2.w, 0.f);
  f3.x = fmaxf(f3.x, 0.f); f3.y = fmaxf(f3.y, 0.f); f3.z = fmaxf(f3.z, 0.f); f3.w = fmaxf(f3.w, 0.f);
  s16x8 a0, a1;
  a0[0] = (short)f2bf(f0.x); a0[1] = (short)f2bf(f0.y);
  a0[2] = (short)f2bf(f0.z); a0[3] = (short)f2bf(f0.w);
  a0[4] = (short)f2bf(f1.x); a0[5] = (short)f2bf(f1.y);
  a0[6] = (short)f2bf(f1.z); a0[7] = (short)f2bf(f1.w);
  a1[0] = (short)f2bf(f2.x); a1[1] = (short)f2bf(f2.y);
  a1[2] = (short)f2bf(f2.z); a1[3] = (short)f2bf(f2.w);
  a1[4] = (short)f2bf(f3.x); a1[5] = (short)f2bf(f3.y);
  a1[6] = (short)f2bf(f3.z); a1[7] = (short)f2bf(f3.w);
  s16x8 b0 = *(const s16x8*)(Wt3 + arow * 64 + g * 8);
  s16x8 b1 = *(const s16x8*)(Wt3 + arow * 64 + 32 + g * 8);
  f32x4 acc = (f32x4){0.f, 0.f, 0.f, 0.f};
  acc = __builtin_amdgcn_mfma_f32_16x16x32_bf16(a0, b0, acc, 0, 0, 0);
  acc = __builtin_amdgcn_mfma_f32_16x16x32_bf16(a1, b1, acc, 0, 0, 0);
  float bb = (arow < 4) ? b[arow] : 0.f;
#pragma unroll
  for (int r2 = 0; r2 < 4; ++r2) {
    float zv = __shfl_xor(acc[r2], 4, 64);
    float rv = __shfl_xor(acc[r2], 8, 64);
    int nd = n0 + g * 4 + r2;
    if (arow < 4 && nd < n) {
      yz3p[(size_t)nd * 4 + arow] = packYZ(acc[r2], zv);
      agg3[(size_t)nd * 4 + arow] = rv + bb;
    }
  }
}

// --------- CSR build: histA -> scanCols -> scatterC -> placeK ---------------

__global__ __launch_bounds__(256) void histA(const int* __restrict__ ei,
                                             int* __restrict__ hist, int ne) {
  __shared__ int h[NBUCK];
  int t = threadIdx.x;
  for (int i = t; i < NBUCK; i += 256) h[i] = 0;
  __syncthreads();
  int chunk = (ne + PART_BLOCKS - 1) / PART_BLOCKS;
  int e0 = blockIdx.x * chunk;
  int e1 = min(ne, e0 + chunk);
  for (int e = e0 + t; e < e1; e += 256)
    atomicAdd(&h[ei[ne + e] >> 8], 1);
  __syncthreads();
  for (int i = t; i < NBUCK; i += 256) hist[blockIdx.x * NBUCK + i] = h[i];
}

__global__ __launch_bounds__(256) void scanCols(int* __restrict__ hist,
                                                int* __restrict__ gTotal) {
  __shared__ int wsum[4];
  int b = blockIdx.x;
  int t = threadIdx.x;
  int v = hist[t * NBUCK + b];
  int lane = t & 63, wid = t >> 6;
  int inc = v;
#pragma unroll
  for (int d = 1; d < 64; d <<= 1) {
    int u = __shfl_up(inc, d, 64);
    if (lane >= d) inc += u;
  }
  if (lane == 63) wsum[wid] = inc;
  __syncthreads();
  if (t == 0) {
    int a = 0;
#pragma unroll
    for (int w = 0; w < 4; ++w) { int tmp = wsum[w]; wsum[w] = a; a += tmp; }
  }
  __syncthreads();
  int excl = wsum[wid] + inc - v;
  hist[t * NBUCK + b] = b * CAPB + excl;
  if (t == 255) gTotal[b] = excl + v;
}

__global__ __launch_bounds__(256) void scatterC(
    const int* __restrict__ ei, const float* __restrict__ ea,
    const int* __restrict__ baseArr, uint2* __restrict__ edgesP, int ne) {
  __shared__ int cnt[NBUCK];
  __shared__ int lbase[NBUCK];
  int t = threadIdx.x;
  for (int i = t; i < NBUCK; i += 256) {
    cnt[i] = 0;
    lbase[i] = baseArr[blockIdx.x * NBUCK + i];
  }
  __syncthreads();
  int chunk = (ne + PART_BLOCKS - 1) / PART_BLOCKS;
  int e0 = blockIdx.x * chunk;
  int e1 = min(ne, e0 + chunk);
  for (int e = e0 + t; e < e1; e += 256) {
    unsigned s = (unsigned)ei[e];
    int dd = ei[ne + e];
    unsigned abits = __float_as_uint(ea[e]);
    int bk = dd >> 8;
    int pos = atomicAdd(&cnt[bk], 1);
    edgesP[lbase[bk] + pos] = make_uint2(s | ((unsigned)(dd & 255) << 20), abits);
  }
}

__global__ __launch_bounds__(256) void placeK(
    const uint2* __restrict__ edgesP, const int* __restrict__ gTotal,
    uint2* __restrict__ edgeS, int* __restrict__ offS, int* __restrict__ offE,
    int n) {
  __shared__ int deg[256];
  __shared__ int cur[256];
  __shared__ int wsum[4];
  int b = blockIdx.x;
  int t = threadIdx.x;
  int base = b * CAPB;
  int cnt = gTotal[b];
  int n0 = b << 8;
  int nn = min(256, n - n0);
  deg[t] = 0;
  __syncthreads();
  for (int i = t; i < cnt; i += 256)
    atomicAdd(&deg[edgesP[base + i].x >> 20], 1);
  __syncthreads();
  int v = deg[t];
  int lane = t & 63, wid = t >> 6;
  int inc = v;
#pragma unroll
  for (int d2 = 1; d2 < 64; d2 <<= 1) {
    int u = __shfl_up(inc, d2, 64);
    if (lane >= d2) inc += u;
  }
  if (lane == 63) wsum[wid] = inc;
  __syncthreads();
  if (t == 0) {
    int a = 0;
#pragma unroll
    for (int w = 0; w < 4; ++w) { int tmp = wsum[w]; wsum[w] = a; a += tmp; }
  }
  __syncthreads();
  int excl = wsum[wid] + inc - v;
  cur[t] = excl;
  if (t < nn) {
    offS[n0 + t] = base + excl;
    offE[n0 + t] = base + excl + v;
  }
  __syncthreads();
  for (int i = t; i < cnt; i += 256) {
    uint2 ent = edgesP[base + i];
    int dl = ent.x >> 20;
    int slot = base + atomicAdd(&cur[dl], 1);
    edgeS[slot] = make_uint2(ent.x & 0xFFFFFu, ent.y);
  }
}

// ---------------- gather-aggregate (wide: 16 lanes per edge) ----------------
// Wave = 1 node. Quarter-wave group g handles edge j0+g (+4 per step); each of
// its 16 lanes reads a uint4 (4 packed dims) of the 256B yzp row. 2-deep
// manual unroll = 8 edges in flight/wave. Epilogue: shfl_xor(16/32) reduces
// the 4 group-partials; group 0 does the float4 agg read-modify-write.
__global__ __launch_bounds__(256) void gather64(
    const int* __restrict__ offS, const int* __restrict__ offE,
    const uint2* __restrict__ edgeS, const unsigned* __restrict__ yzp,
    float* __restrict__ agg, int n) {
  int node = (blockIdx.x * 256 + threadIdx.x) >> 6;
  int lane = threadIdx.x & 63;
  if (node >= n) return;
  int grp = lane >> 4, l16 = lane & 15;
  int j0 = offS[node];
  int jend = offE[node];
  float a0 = 0.f, a1 = 0.f, a2 = 0.f, a3 = 0.f;
  int j = j0 + grp;
#pragma unroll 1
  for (; j + 4 < jend; j += 8) {
    uint2 edA = edgeS[j];
    uint2 edB = edgeS[j + 4];
    uint4 rA = *(const uint4*)(yzp + (size_t)edA.x * 64 + l16 * 4);
    uint4 rB = *(const uint4*)(yzp + (size_t)edB.x * 64 + l16 * 4);
    float eA = __uint_as_float(edA.y);
    float eB = __uint_as_float(edB.y);
    a0 += fmaf(eA, bfLo(rA.x), bfHi(rA.x));
    a1 += fmaf(eA, bfLo(rA.y), bfHi(rA.y));
    a2 += fmaf(eA, bfLo(rA.z), bfHi(rA.z));
    a3 += fmaf(eA, bfLo(rA.w), bfHi(rA.w));
    a0 += fmaf(eB, bfLo(rB.x), bfHi(rB.x));
    a1 += fmaf(eB, bfLo(rB.y), bfHi(rB.y));
    a2 += fmaf(eB, bfLo(rB.z), bfHi(rB.z));
    a3 += fmaf(eB, bfLo(rB.w), bfHi(rB.w));
  }
  if (j < jend) {
    uint2 ed = edgeS[j];
    uint4 r = *(const uint4*)(yzp + (size_t)ed.x * 64 + l16 * 4);
    float e = __uint_as_float(ed.y);
    a0 += fmaf(e, bfLo(r.x), bfHi(r.x));
    a1 += fmaf(e, bfLo(r.y), bfHi(r.y));
    a2 += fmaf(e, bfLo(r.z), bfHi(r.z));
    a3 += fmaf(e, bfLo(r.w), bfHi(r.w));
  }
  // reduce the 4 group-partials (lanes l16, l16+16, l16+32, l16+48)
  a0 += __shfl_xor(a0, 16, 64); a0 += __shfl_xor(a0, 32, 64);
  a1 += __shfl_xor(a1, 16, 64); a1 += __shfl_xor(a1, 32, 64);
  a2 += __shfl_xor(a2, 16, 64); a2 += __shfl_xor(a2, 32, 64);
  a3 += __shfl_xor(a3, 16, 64); a3 += __shfl_xor(a3, 32, 64);
  if (grp == 0) {
    float* ap = agg + (size_t)node * 64 + l16 * 4;
    float4 init = *(const float4*)ap;
    init.x += a0; init.y += a1; init.z += a2; init.w += a3;
    *(float4*)ap = init;
  }
}

__global__ __launch_bounds__(256) void gather4_logsm(
    const int* __restrict__ offS, const int* __restrict__ offE,
    const uint2* __restrict__ edgeS, const unsigned* __restrict__ yz3p,
    const float* __restrict__ agg3, float* __restrict__ out, int n) {
  int idx = blockIdx.x * 256 + threadIdx.x;
  int node = idx >> 2;
  int o = idx & 3;
  if (node >= n) return;
  int j = offS[node];
  int jend = offE[node];
  float acc = agg3[(size_t)node * 4 + o];
#pragma unroll 1
  for (; j < jend; ++j) {
    uint2 ed = edgeS[j];
    unsigned p = yz3p[(size_t)ed.x * 4 + o];
    acc += fmaf(__uint_as_float(ed.y), bfLo(p), bfHi(p));
  }
  float m = acc;
  m = fmaxf(m, __shfl_xor(m, 1, 4));
  m = fmaxf(m, __shfl_xor(m, 2, 4));
  float s = expf(acc - m);
  s += __shfl_xor(s, 1, 4);
  s += __shfl_xor(s, 2, 4);
  out[(size_t)node * 4 + o] = acc - m - logf(s);
}

// ---------------- launch -----------------------------------------------------

extern "C" void kernel_launch(void* const* d_in, const int* in_sizes, int n_in,
                              void* d_out, int out_size, void* d_ws, size_t ws_size,
                              hipStream_t stream) {
  const float* x = (const float*)d_in[0];
  const int* ei = (const int*)d_in[1];
  const float* ea = (const float*)d_in[2];
  const float* We1 = (const float*)d_in[3];
  const float* be1 = (const float*)d_in[4];
  const float* Wr1 = (const float*)d_in[5];
  const float* b1 = (const float*)d_in[6];
  const float* We2 = (const float*)d_in[7];
  const float* be2 = (const float*)d_in[8];
  const float* Wr2 = (const float*)d_in[9];
  const float* b2 = (const float*)d_in[10];
  const float* We3 = (const float*)d_in[11];
  const float* be3 = (const float*)d_in[12];
  const float* Wr3 = (const float*)d_in[13];
  const float* b3 = (const float*)d_in[14];

  const int N = in_sizes[0] / D;  // 100000
  const int E = in_sizes[2];      // 1600000
  const size_t EREG = (size_t)NBUCK * CAPB;  // padded CSR storage (~1.86M entries)

  // ws layout. edgesP aliases agg2; agg3/yz3p alias agg1.
  char* ws = (char*)d_ws;
  uint2* edgeS = (uint2*)ws;                                 // EREG * 8B
  unsigned* yzp = (unsigned*)(ws + EREG * 8);                // N*64 * 4B
  float* agg1 = (float*)((char*)yzp + (size_t)N * 64 * 4);   // N*64
  float* agg2 = agg1 + (size_t)N * 64;                       // N*64
  int* offS = (int*)(agg2 + (size_t)N * 64);                 // N
  int* offE = offS + N;                                      // N
  int* gTotal = offE + N;                                    // NBUCK
  int* hist = gTotal + NBUCK;                                // PART_BLOCKS*NBUCK
  unsigned short* Wt = (unsigned short*)(hist + PART_BLOCKS * NBUCK);  // 2*12288+1024 bf16
  uint2* edgesP = (uint2*)agg2;                              // alias
  float* agg3 = agg1;                                        // alias
  unsigned* yz3p = (unsigned*)(agg1 + (size_t)N * 4);        // alias
  float* out = (float*)d_out;

  int tblocksM = (N + 63) / 64;            // transformM/transform3M: 64 nodes/block
  int g64blocks = (int)(((long long)N * 64 + 255) / 256);
  int g4blocks = (int)(((long long)N * 4 + 255) / 256);

  // ---- weight prep + CSR build (deterministic counting sort) ----
  wprep<<<3, 256, 0, stream>>>(We1, be1, Wr1, We2, be2, Wr2, We3, be3, Wr3, Wt);
  histA<<<PART_BLOCKS, 256, 0, stream>>>(ei, hist, E);
  scanCols<<<NBUCK, 256, 0, stream>>>(hist, gTotal);
  scatterC<<<PART_BLOCKS, 256, 0, stream>>>(ei, ea, hist, edgesP, E);
  placeK<<<NBUCK, 256, 0, stream>>>(edgesP, gTotal, edgeS, offS, offE, N);

  // ---- Layer 1: x -> agg1 ----
  transformM<false><<<tblocksM, 256, 0, stream>>>(x, Wt, b1, yzp, agg1, N);
  gather64<<<g64blocks, 256, 0, stream>>>(offS, offE, edgeS, yzp, agg1, N);
  // ---- Layer 2: relu(agg1) -> agg2 ----
  transformM<true><<<tblocksM, 256, 0, stream>>>(agg1, Wt + 12288, b2, yzp, agg2, N);
  gather64<<<g64blocks, 256, 0, stream>>>(offS, offE, edgeS, yzp, agg2, N);
  // ---- Layer 3: relu(agg2) -> out (fused log_softmax) ----
  transform3M<<<tblocksM, 256, 0, stream>>>(agg2, Wt + 24576, b3, yz3p, agg3, N);
  gather4_logsm<<<g4blocks, 256, 0, stream>>>(offS, offE, edgeS, yz3p, agg3, out, N);
}

// Round 10
// 310.205 us; speedup vs baseline: 3.8839x; 1.0826x over previous
//
#include <hip/hip_runtime.h>
#include <math.h>

#define D 64
#define NBUCK 392         // buckets of 256 nodes: bucket = dst >> 8 (392*256=100352)
#define CAPB 4736         // fixed bucket capacity: mean 4096 + 10 sigma, 8-entry aligned
#define PART_BLOCKS 256

typedef __attribute__((ext_vector_type(4))) float f32x4;
typedef __attribute__((ext_vector_type(8))) short s16x8;

// ---- bf16 pack helpers (RNE) ----
__device__ __forceinline__ unsigned short f2bf(float f) {
  unsigned u = __float_as_uint(f);
  unsigned r = (u + 0x7fff + ((u >> 16) & 1)) >> 16;
  return (unsigned short)r;
}
__device__ __forceinline__ float bfLo(unsigned p) { return __uint_as_float(p << 16); }
__device__ __forceinline__ float bfHi(unsigned p) { return __uint_as_float(p & 0xffff0000u); }
__device__ __forceinline__ unsigned packYZ(float y, float z) {
  return (unsigned)f2bf(y) | ((unsigned)f2bf(z) << 16);
}

// ------- weight prep ---------------------------------------------------------
// blocks 0,1: Wt[l] = bf16 [64][192] rows=output o, cols k: [Wm|Bm|Wr] stacked.
// block 2:    Wt3   = bf16 [16][64], rows = [We3|be3|Wr3|0]^T.

__global__ void wprep(const float* __restrict__ We1, const float* __restrict__ be1,
                      const float* __restrict__ Wr1, const float* __restrict__ We2,
                      const float* __restrict__ be2, const float* __restrict__ Wr2,
                      const float* __restrict__ We3, const float* __restrict__ be3,
                      const float* __restrict__ Wr3, unsigned short* __restrict__ Wt) {
  int l = blockIdx.x;
  if (l == 2) {
    unsigned short* Wt3 = Wt + 24576;
    for (int idx = threadIdx.x; idx < 1024; idx += 256) {
      int r = idx >> 6, k = idx & 63;
      int sel = r >> 2, o = r & 3;
      float v = (sel == 0) ? We3[k * 4 + o]
              : (sel == 1) ? be3[k * 4 + o]
              : (sel == 2) ? Wr3[k * 4 + o] : 0.f;
      Wt3[idx] = f2bf(v);
    }
    return;
  }
  const float* We = l ? We2 : We1;
  const float* be = l ? be2 : be1;
  const float* Wr = l ? Wr2 : Wr1;
  for (int idx = threadIdx.x; idx < 12288; idx += 256) {
    int o = idx / 192, k = idx % 192;
    float v = (k < 64)  ? We[k * 64 + o]
            : (k < 128) ? be[(k - 64) * 64 + o]
                        : Wr[(k - 128) * 64 + o];
    Wt[l * 12288 + idx] = f2bf(v);
  }
}

// ------- xprep: bf16 copy of x ----------------------------------------------
__global__ __launch_bounds__(256) void xprep(const float* __restrict__ x,
                                             unsigned short* __restrict__ xb, int n64) {
  int idx = (blockIdx.x * 256 + threadIdx.x) * 4;
  if (idx >= n64) return;
  float4 v = *(const float4*)(x + idx);
  ushort4 o;
  o.x = f2bf(v.x); o.y = f2bf(v.y); o.z = f2bf(v.z); o.w = f2bf(v.w);
  *(ushort4*)(xb + idx) = o;
}

// ---------------- combine transform: hnext = relu(S1@Wm + S0@Bm + hb@Wr + b) -
// A = [cvt(S1) | cvt(S0) | hb] (K=192 bf16), B^T = Wt' [64][192] in LDS
// (XOR-swizzled ^((o&7)<<4): row stride 384B is bank-degenerate without it).
// Wave = 16 nodes, 4 output tiles x 6 K-chunks = 24 MFMA.
__global__ __launch_bounds__(256) void transformC(
    const float* __restrict__ S, const unsigned short* __restrict__ hb,
    const unsigned short* __restrict__ WtP, const float* __restrict__ b,
    unsigned short* __restrict__ hbOut, int n) {
  __shared__ uint4 ldsW4[1536];  // 24 KB
  char* ldsW = (char*)ldsW4;
  int t = threadIdx.x;
  const uint4* wg = (const uint4*)WtP;
#pragma unroll
  for (int i = 0; i < 6; ++i) {
    int idx = t + i * 256;
    int off = idx * 16;
    int row = idx / 24;  // 24 uint4 per 384B row
    *(uint4*)(ldsW + (off ^ ((row & 7) << 4))) = wg[idx];
  }
  __syncthreads();
  int wid = t >> 6, lane = t & 63;
  int n0 = blockIdx.x * 64 + wid * 16;
  if (n0 >= n) return;
  int arow = lane & 15, g = lane >> 4;
  int nodeA = min(n0 + arow, n - 1);
  const float* Sp = S + (size_t)nodeA * 128;
  s16x8 a[6];
#pragma unroll
  for (int c = 0; c < 4; ++c) {  // chunks 0-1: S1, 2-3: S0
    float4 fa = *(const float4*)(Sp + c * 32 + g * 8);
    float4 fb = *(const float4*)(Sp + c * 32 + g * 8 + 4);
    a[c][0] = (short)f2bf(fa.x); a[c][1] = (short)f2bf(fa.y);
    a[c][2] = (short)f2bf(fa.z); a[c][3] = (short)f2bf(fa.w);
    a[c][4] = (short)f2bf(fb.x); a[c][5] = (short)f2bf(fb.y);
    a[c][6] = (short)f2bf(fb.z); a[c][7] = (short)f2bf(fb.w);
  }
  const unsigned short* hp = hb + (size_t)nodeA * 64;
  a[4] = *(const s16x8*)(hp + g * 8);
  a[5] = *(const s16x8*)(hp + 32 + g * 8);

  f32x4 acc[4];
#pragma unroll
  for (int tt = 0; tt < 4; ++tt) acc[tt] = (f32x4){0.f, 0.f, 0.f, 0.f};
#pragma unroll
  for (int tt = 0; tt < 4; ++tt) {
    int o = tt * 16 + arow;
    int sw = (o & 7) << 4;
    int rb = o * 384;
#pragma unroll
    for (int c = 0; c < 6; ++c) {
      s16x8 bf = *(const s16x8*)(ldsW + ((rb + c * 64 + g * 16) ^ sw));
      acc[tt] = __builtin_amdgcn_mfma_f32_16x16x32_bf16(a[c], bf, acc[tt], 0, 0, 0);
    }
  }
  // epilogue: D col = arow within tile, row(node) = g*4 + r2; relu + bf16
#pragma unroll
  for (int tt = 0; tt < 4; ++tt) {
    float bb = b[tt * 16 + arow];
#pragma unroll
    for (int r2 = 0; r2 < 4; ++r2) {
      int nd = n0 + g * 4 + r2;
      if (nd < n)
        hbOut[(size_t)nd * 64 + tt * 16 + arow] = f2bf(fmaxf(acc[tt][r2] + bb, 0.f));
    }
  }
}

// ------- MFMA layer-3 transform: [n x 64 bf16] @ [64 x 16] ------------------
__global__ __launch_bounds__(256) void transform3M(
    const unsigned short* __restrict__ hb, const unsigned short* __restrict__ Wt3,
    const float* __restrict__ b, unsigned* __restrict__ yz3p,
    float* __restrict__ agg3, int n) {
  int t = threadIdx.x;
  int wid = t >> 6, lane = t & 63;
  int n0 = blockIdx.x * 64 + wid * 16;
  if (n0 >= n) return;
  int arow = lane & 15, g = lane >> 4;
  int nodeA = min(n0 + arow, n - 1);
  const unsigned short* hp = hb + (size_t)nodeA * 64;
  s16x8 a0 = *(const s16x8*)(hp + g * 8);        // hb already relu'd
  s16x8 a1 = *(const s16x8*)(hp + 32 + g * 8);
  s16x8 b0 = *(const s16x8*)(Wt3 + arow * 64 + g * 8);
  s16x8 b1 = *(const s16x8*)(Wt3 + arow * 64 + 32 + g * 8);
  f32x4 acc = (f32x4){0.f, 0.f, 0.f, 0.f};
  acc = __builtin_amdgcn_mfma_f32_16x16x32_bf16(a0, b0, acc, 0, 0, 0);
  acc = __builtin_amdgcn_mfma_f32_16x16x32_bf16(a1, b1, acc, 0, 0, 0);
  float bb = (arow < 4) ? b[arow] : 0.f;
#pragma unroll
  for (int r2 = 0; r2 < 4; ++r2) {
    float zv = __shfl_xor(acc[r2], 4, 64);
    float rv = __shfl_xor(acc[r2], 8, 64);
    int nd = n0 + g * 4 + r2;
    if (arow < 4 && nd < n) {
      yz3p[(size_t)nd * 4 + arow] = packYZ(acc[r2], zv);
      agg3[(size_t)nd * 4 + arow] = rv + bb;
    }
  }
}

// --------- CSR build: histA -> scanCols -> scatterC -> placeK ---------------

__global__ __launch_bounds__(256) void histA(const int* __restrict__ ei,
                                             int* __restrict__ hist, int ne) {
  __shared__ int h[NBUCK];
  int t = threadIdx.x;
  for (int i = t; i < NBUCK; i += 256) h[i] = 0;
  __syncthreads();
  int chunk = (ne + PART_BLOCKS - 1) / PART_BLOCKS;
  int e0 = blockIdx.x * chunk;
  int e1 = min(ne, e0 + chunk);
  for (int e = e0 + t; e < e1; e += 256)
    atomicAdd(&h[ei[ne + e] >> 8], 1);
  __syncthreads();
  for (int i = t; i < NBUCK; i += 256) hist[blockIdx.x * NBUCK + i] = h[i];
}

__global__ __launch_bounds__(256) void scanCols(int* __restrict__ hist,
                                                int* __restrict__ gTotal) {
  __shared__ int wsum[4];
  int b = blockIdx.x;
  int t = threadIdx.x;
  int v = hist[t * NBUCK + b];
  int lane = t & 63, wid = t >> 6;
  int inc = v;
#pragma unroll
  for (int d = 1; d < 64; d <<= 1) {
    int u = __shfl_up(inc, d, 64);
    if (lane >= d) inc += u;
  }
  if (lane == 63) wsum[wid] = inc;
  __syncthreads();
  if (t == 0) {
    int a = 0;
#pragma unroll
    for (int w = 0; w < 4; ++w) { int tmp = wsum[w]; wsum[w] = a; a += tmp; }
  }
  __syncthreads();
  int excl = wsum[wid] + inc - v;
  hist[t * NBUCK + b] = b * CAPB + excl;
  if (t == 255) gTotal[b] = excl + v;
}

__global__ __launch_bounds__(256) void scatterC(
    const int* __restrict__ ei, const float* __restrict__ ea,
    const int* __restrict__ baseArr, uint2* __restrict__ edgesP, int ne) {
  __shared__ int cnt[NBUCK];
  __shared__ int lbase[NBUCK];
  int t = threadIdx.x;
  for (int i = t; i < NBUCK; i += 256) {
    cnt[i] = 0;
    lbase[i] = baseArr[blockIdx.x * NBUCK + i];
  }
  __syncthreads();
  int chunk = (ne + PART_BLOCKS - 1) / PART_BLOCKS;
  int e0 = blockIdx.x * chunk;
  int e1 = min(ne, e0 + chunk);
  for (int e = e0 + t; e < e1; e += 256) {
    unsigned s = (unsigned)ei[e];
    int dd = ei[ne + e];
    unsigned abits = __float_as_uint(ea[e]);
    int bk = dd >> 8;
    int pos = atomicAdd(&cnt[bk], 1);
    edgesP[lbase[bk] + pos] = make_uint2(s | ((unsigned)(dd & 255) << 20), abits);
  }
}

__global__ __launch_bounds__(256) void placeK(
    const uint2* __restrict__ edgesP, const int* __restrict__ gTotal,
    uint2* __restrict__ edgeS, int* __restrict__ offS, int* __restrict__ offE,
    int n) {
  __shared__ int deg[256];
  __shared__ int cur[256];
  __shared__ int wsum[4];
  int b = blockIdx.x;
  int t = threadIdx.x;
  int base = b * CAPB;
  int cnt = gTotal[b];
  int n0 = b << 8;
  int nn = min(256, n - n0);
  deg[t] = 0;
  __syncthreads();
  for (int i = t; i < cnt; i += 256)
    atomicAdd(&deg[edgesP[base + i].x >> 20], 1);
  __syncthreads();
  int v = deg[t];
  int lane = t & 63, wid = t >> 6;
  int inc = v;
#pragma unroll
  for (int d2 = 1; d2 < 64; d2 <<= 1) {
    int u = __shfl_up(inc, d2, 64);
    if (lane >= d2) inc += u;
  }
  if (lane == 63) wsum[wid] = inc;
  __syncthreads();
  if (t == 0) {
    int a = 0;
#pragma unroll
    for (int w = 0; w < 4; ++w) { int tmp = wsum[w]; wsum[w] = a; a += tmp; }
  }
  __syncthreads();
  int excl = wsum[wid] + inc - v;
  cur[t] = excl;
  if (t < nn) {
    offS[n0 + t] = base + excl;
    offE[n0 + t] = base + excl + v;
  }
  __syncthreads();
  for (int i = t; i < cnt; i += 256) {
    uint2 ent = edgesP[base + i];
    int dl = ent.x >> 20;
    int slot = base + atomicAdd(&cur[dl], 1);
    edgeS[slot] = make_uint2(ent.x & 0xFFFFFu, ent.y);
  }
}

// ---------------- gather2: S1=Σe·hb[src], S0=Σhb[src] (raw-h gather) --------
// Wave = 1 node. 4 groups of 16 lanes; group g handles edge j0+g (+4/step);
// lane reads uint2 (8B = 4 bf16 dims) of the 128B hb row; 2-deep unroll.
// Reduce group-partials via shfl_xor(16/32); group 0 writes S1|S0 (f32).
__global__ __launch_bounds__(256) void gather2(
    const int* __restrict__ offS, const int* __restrict__ offE,
    const uint2* __restrict__ edgeS, const unsigned short* __restrict__ hb,
    float* __restrict__ S, int n) {
  int node = (blockIdx.x * 256 + threadIdx.x) >> 6;
  int lane = threadIdx.x & 63;
  if (node >= n) return;
  int grp = lane >> 4, l16 = lane & 15;
  int j0 = offS[node];
  int jend = offE[node];
  float s10 = 0.f, s11 = 0.f, s12 = 0.f, s13 = 0.f;
  float s00 = 0.f, s01 = 0.f, s02 = 0.f, s03 = 0.f;
  int j = j0 + grp;
#pragma unroll 1
  for (; j + 4 < jend; j += 8) {
    uint2 edA = edgeS[j];
    uint2 edB = edgeS[j + 4];
    uint2 rA = *(const uint2*)(hb + (size_t)edA.x * 64 + l16 * 4);
    uint2 rB = *(const uint2*)(hb + (size_t)edB.x * 64 + l16 * 4);
    float eA = __uint_as_float(edA.y);
    float eB = __uint_as_float(edB.y);
    float v0 = bfLo(rA.x), v1 = bfHi(rA.x), v2 = bfLo(rA.y), v3 = bfHi(rA.y);
    s10 = fmaf(eA, v0, s10); s00 += v0;
    s11 = fmaf(eA, v1, s11); s01 += v1;
    s12 = fmaf(eA, v2, s12); s02 += v2;
    s13 = fmaf(eA, v3, s13); s03 += v3;
    v0 = bfLo(rB.x); v1 = bfHi(rB.x); v2 = bfLo(rB.y); v3 = bfHi(rB.y);
    s10 = fmaf(eB, v0, s10); s00 += v0;
    s11 = fmaf(eB, v1, s11); s01 += v1;
    s12 = fmaf(eB, v2, s12); s02 += v2;
    s13 = fmaf(eB, v3, s13); s03 += v3;
  }
  if (j < jend) {
    uint2 ed = edgeS[j];
    uint2 r = *(const uint2*)(hb + (size_t)ed.x * 64 + l16 * 4);
    float e = __uint_as_float(ed.y);
    float v0 = bfLo(r.x), v1 = bfHi(r.x), v2 = bfLo(r.y), v3 = bfHi(r.y);
    s10 = fmaf(e, v0, s10); s00 += v0;
    s11 = fmaf(e, v1, s11); s01 += v1;
    s12 = fmaf(e, v2, s12); s02 += v2;
    s13 = fmaf(e, v3, s13); s03 += v3;
  }
  s10 += __shfl_xor(s10, 16, 64); s10 += __shfl_xor(s10, 32, 64);
  s11 += __shfl_xor(s11, 16, 64); s11 += __shfl_xor(s11, 32, 64);
  s12 += __shfl_xor(s12, 16, 64); s12 += __shfl_xor(s12, 32, 64);
  s13 += __shfl_xor(s13, 16, 64); s13 += __shfl_xor(s13, 32, 64);
  s00 += __shfl_xor(s00, 16, 64); s00 += __shfl_xor(s00, 32, 64);
  s01 += __shfl_xor(s01, 16, 64); s01 += __shfl_xor(s01, 32, 64);
  s02 += __shfl_xor(s02, 16, 64); s02 += __shfl_xor(s02, 32, 64);
  s03 += __shfl_xor(s03, 16, 64); s03 += __shfl_xor(s03, 32, 64);
  if (grp == 0) {
    float* sp = S + (size_t)node * 128 + l16 * 4;
    *(float4*)sp = make_float4(s10, s11, s12, s13);
    *(float4*)(sp + 64) = make_float4(s00, s01, s02, s03);
  }
}

__global__ __launch_bounds__(256) void gather4_logsm(
    const int* __restrict__ offS, const int* __restrict__ offE,
    const uint2* __restrict__ edgeS, const unsigned* __restrict__ yz3p,
    const float* __restrict__ agg3, float* __restrict__ out, int n) {
  int idx = blockIdx.x * 256 + threadIdx.x;
  int node = idx >> 2;
  int o = idx & 3;
  if (node >= n) return;
  int j = offS[node];
  int jend = offE[node];
  float acc = agg3[(size_t)node * 4 + o];
#pragma unroll 1
  for (; j < jend; ++j) {
    uint2 ed = edgeS[j];
    unsigned p = yz3p[(size_t)ed.x * 4 + o];
    acc += fmaf(__uint_as_float(ed.y), bfLo(p), bfHi(p));
  }
  float m = acc;
  m = fmaxf(m, __shfl_xor(m, 1, 4));
  m = fmaxf(m, __shfl_xor(m, 2, 4));
  float s = expf(acc - m);
  s += __shfl_xor(s, 1, 4);
  s += __shfl_xor(s, 2, 4);
  out[(size_t)node * 4 + o] = acc - m - logf(s);
}

// ---------------- launch -----------------------------------------------------

extern "C" void kernel_launch(void* const* d_in, const int* in_sizes, int n_in,
                              void* d_out, int out_size, void* d_ws, size_t ws_size,
                              hipStream_t stream) {
  const float* x = (const float*)d_in[0];
  const int* ei = (const int*)d_in[1];
  const float* ea = (const float*)d_in[2];
  const float* We1 = (const float*)d_in[3];
  const float* be1 = (const float*)d_in[4];
  const float* Wr1 = (const float*)d_in[5];
  const float* b1 = (const float*)d_in[6];
  const float* We2 = (const float*)d_in[7];
  const float* be2 = (const float*)d_in[8];
  const float* Wr2 = (const float*)d_in[9];
  const float* b2 = (const float*)d_in[10];
  const float* We3 = (const float*)d_in[11];
  const float* be3 = (const float*)d_in[12];
  const float* Wr3 = (const float*)d_in[13];
  const float* b3 = (const float*)d_in[14];

  const int N = in_sizes[0] / D;  // 100000
  const int E = in_sizes[2];      // 1600000
  const size_t EREG = (size_t)NBUCK * CAPB;  // padded CSR storage (~1.86M entries)

  // ws layout. edgesP aliases S (dead before first gather2); hb3 aliases xb
  // (xb dead after L1 transformC).
  char* ws = (char*)d_ws;
  uint2* edgeS = (uint2*)ws;                                 // EREG * 8B
  float* S = (float*)(ws + EREG * 8);                        // N*128 f32 (S1|S0)
  unsigned short* xb = (unsigned short*)(S + (size_t)N * 128);  // N*64 bf16
  unsigned short* hb2 = xb + (size_t)N * 64;                 // N*64 bf16
  unsigned* yz3p = (unsigned*)(hb2 + (size_t)N * 64);        // N*4
  float* agg3 = (float*)(yz3p + (size_t)N * 4);              // N*4
  int* offS = (int*)(agg3 + (size_t)N * 4);                  // N
  int* offE = offS + N;                                      // N
  int* gTotal = offE + N;                                    // NBUCK
  int* hist = gTotal + NBUCK;                                // PART_BLOCKS*NBUCK
  unsigned short* Wt = (unsigned short*)(hist + PART_BLOCKS * NBUCK);  // 25600 bf16
  uint2* edgesP = (uint2*)S;                                 // alias
  unsigned short* hb3 = xb;                                  // alias
  float* out = (float*)d_out;

  int tblocksM = (N + 63) / 64;            // transformC/transform3M: 64 nodes/block
  int g64blocks = (int)(((long long)N * 64 + 255) / 256);
  int g4blocks = (int)(((long long)N * 4 + 255) / 256);
  int xblocks = (int)(((long long)N * 64 / 4 + 255) / 256);

  // ---- prep + CSR build (deterministic counting sort) ----
  wprep<<<3, 256, 0, stream>>>(We1, be1, Wr1, We2, be2, Wr2, We3, be3, Wr3, Wt);
  xprep<<<xblocks, 256, 0, stream>>>(x, xb, N * 64);
  histA<<<PART_BLOCKS, 256, 0, stream>>>(ei, hist, E);
  scanCols<<<NBUCK, 256, 0, stream>>>(hist, gTotal);
  scatterC<<<PART_BLOCKS, 256, 0, stream>>>(ei, ea, hist, edgesP, E);
  placeK<<<NBUCK, 256, 0, stream>>>(edgesP, gTotal, edgeS, offS, offE, N);

  // ---- Layer 1: gather raw x, then combine-transform -> hb2 ----
  gather2<<<g64blocks, 256, 0, stream>>>(offS, offE, edgeS, xb, S, N);
  transformC<<<tblocksM, 256, 0, stream>>>(S, xb, Wt, b1, hb2, N);
  // ---- Layer 2 ----
  gather2<<<g64blocks, 256, 0, stream>>>(offS, offE, edgeS, hb2, S, N);
  transformC<<<tblocksM, 256, 0, stream>>>(S, hb2, Wt + 12288, b2, hb3, N);
  // ---- Layer 3: cheap packed path (16B rows) + fused log_softmax ----
  transform3M<<<tblocksM, 256, 0, stream>>>(hb3, Wt + 24576, b3, yz3p, agg3, N);
  gather4_logsm<<<g4blocks, 256, 0, stream>>>(offS, offE, edgeS, yz3p, agg3, out, N);
}